// Round 4
// baseline (4388.469 us; speedup 1.0000x reference)
//
#include <hip/hip_runtime.h>
#include <math.h>

#define TD 192
#define HD 48
#define KSEL 128
#define QB 4

// Map float to orderable unsigned: a > b (float) <=> f2o(a) > f2o(b)
__device__ __forceinline__ unsigned f2o(float f) {
  unsigned u = __float_as_uint(f);
  return (u & 0x80000000u) ? ~u : (u | 0x80000000u);
}
__device__ __forceinline__ float o2f(unsigned u) {
  unsigned v = (u & 0x80000000u) ? (u & 0x7fffffffu) : ~u;
  return __uint_as_float(v);
}

// 2D sinusoidal positional encoding, matches reference _pos_enc.
__global__ void pe_kernel(float* __restrict__ pe, int W) {
  int n = blockIdx.x;
  int t = threadIdx.x;                      // 0..191
  const float c = -0.09594104554885301f;    // -ln(10000)/96
  float val;
  if (t < 96) {
    float dv = expf((float)t * c);
    val = sinf((float)(n % W) * dv);
  } else {
    float dv = expf((float)(t - 96) * c);
    val = cosf((float)(n / W) * dv);
  }
  pe[n * TD + t] = val;
}

// Q = f1@qw+qb+pe (row-major [b][n][td])
// Kt = transpose of (f2@kw+kb+pe) -> [b][h][d][N]
// V = f2@vw+vb (row-major)
__global__ void qkv_kernel(const float* __restrict__ feat1, const float* __restrict__ feat2,
                           const float* __restrict__ qw, const float* __restrict__ qb,
                           const float* __restrict__ kw, const float* __restrict__ kb,
                           const float* __restrict__ vw, const float* __restrict__ vb,
                           const float* __restrict__ pe,
                           float* __restrict__ Q, float* __restrict__ Kt, float* __restrict__ V,
                           int C, int N) {
  int t = threadIdx.x;            // 0..191
  int bn = blockIdx.x;            // b*N + n
  int b = bn / N, n = bn - b * N;
  const float* f1 = feat1 + (size_t)b * C * N + n;
  const float* f2 = feat2 + (size_t)b * C * N + n;
  float q = 0.f, k = 0.f, v = 0.f;
  for (int c = 0; c < C; ++c) {
    float a1 = f1[(size_t)c * N];
    float a2 = f2[(size_t)c * N];
    q = fmaf(a1, qw[c * TD + t], q);
    k = fmaf(a2, kw[c * TD + t], k);
    v = fmaf(a2, vw[c * TD + t], v);
  }
  float p = pe[n * TD + t];
  size_t o = (size_t)bn * TD + t;
  Q[o] = q + qb[t] + p;
  V[o] = v + vb[t];
  int h = t / HD, d = t - h * HD;
  Kt[(((size_t)b * 4 + h) * HD + d) * N + n] = k + kb[t] + p;
}

// One block per (b, h, group of QB=4 queries). Score GEMM is block-cooperative
// through a CHUNK-key LDS window (32KB max) so 3 blocks/CU fit; wave w keeps
// query w's full key set in registers (uint4 vectorized handoff), then does
// radix-select top-128 with exact lowest-index tie ranking, softmax, V gather.
template <int N>
__global__ __launch_bounds__(256, 3) void attn_kernel(
    const float* __restrict__ Q, const float* __restrict__ Kt, const float* __restrict__ V,
    float* __restrict__ O) {
  constexpr int CHUNK = (N > 2048) ? 2048 : N;   // LDS staging window
  constexpr int NCH = N / CHUNK;
  constexpr int NQ4 = CHUNK / 256;               // uint4 regs per lane per chunk
  constexpr int NV4 = N / 256;                   // total uint4 regs per lane
  extern __shared__ unsigned sb[];               // QB * CHUNK keys
  __shared__ float qv[QB][HD];
  __shared__ unsigned hist[4][256];
  __shared__ int idxb[4][KSEL];
  __shared__ float wb[4][KSEL];

  const int tid = threadIdx.x;
  const int nq = N / QB;
  const int qg = blockIdx.x % nq;
  const int h = (blockIdx.x / nq) & 3;
  const int b = blockIdx.x / (4 * nq);
  const int q0 = qg * QB;
  const float scale = 0.14433756729740643f;  // 1/sqrt(48)

  if (tid < QB * HD) {
    int q = tid / HD, d = tid - q * HD;
    qv[q][d] = Q[((size_t)(b * N + q0 + q)) * TD + h * HD + d];
  }
  __syncthreads();

  const int w = tid >> 6, lane = tid & 63;
  const unsigned long long lanelt = (1ull << lane) - 1ull;
  const float* kt = Kt + ((size_t)(b * 4 + h) * HD) * N;
  uint4 key[NV4];

  // ---- chunked score GEMM -> LDS -> per-wave registers ----
  for (int ch = 0; ch < NCH; ++ch) {
    const int jbase = ch * CHUNK;
    for (int j0 = tid * 4; j0 < CHUNK; j0 += 1024) {
      float4 acc[QB];
#pragma unroll
      for (int q = 0; q < QB; ++q) acc[q] = make_float4(0.f, 0.f, 0.f, 0.f);
#pragma unroll
      for (int d4 = 0; d4 < HD; d4 += 4) {
        float4 k0 = *reinterpret_cast<const float4*>(kt + (size_t)(d4 + 0) * N + jbase + j0);
        float4 k1 = *reinterpret_cast<const float4*>(kt + (size_t)(d4 + 1) * N + jbase + j0);
        float4 k2 = *reinterpret_cast<const float4*>(kt + (size_t)(d4 + 2) * N + jbase + j0);
        float4 k3 = *reinterpret_cast<const float4*>(kt + (size_t)(d4 + 3) * N + jbase + j0);
#pragma unroll
        for (int q = 0; q < QB; ++q) {
          float4 qq = *reinterpret_cast<const float4*>(&qv[q][d4]);
          acc[q].x = fmaf(qq.x, k0.x, acc[q].x); acc[q].x = fmaf(qq.y, k1.x, acc[q].x);
          acc[q].x = fmaf(qq.z, k2.x, acc[q].x); acc[q].x = fmaf(qq.w, k3.x, acc[q].x);
          acc[q].y = fmaf(qq.x, k0.y, acc[q].y); acc[q].y = fmaf(qq.y, k1.y, acc[q].y);
          acc[q].y = fmaf(qq.z, k2.y, acc[q].y); acc[q].y = fmaf(qq.w, k3.y, acc[q].y);
          acc[q].z = fmaf(qq.x, k0.z, acc[q].z); acc[q].z = fmaf(qq.y, k1.z, acc[q].z);
          acc[q].z = fmaf(qq.z, k2.z, acc[q].z); acc[q].z = fmaf(qq.w, k3.z, acc[q].z);
          acc[q].w = fmaf(qq.x, k0.w, acc[q].w); acc[q].w = fmaf(qq.y, k1.w, acc[q].w);
          acc[q].w = fmaf(qq.z, k2.w, acc[q].w); acc[q].w = fmaf(qq.w, k3.w, acc[q].w);
        }
      }
#pragma unroll
      for (int q = 0; q < QB; ++q) {
        uint4 kk;
        kk.x = f2o(acc[q].x * scale); kk.y = f2o(acc[q].y * scale);
        kk.z = f2o(acc[q].z * scale); kk.w = f2o(acc[q].w * scale);
        *reinterpret_cast<uint4*>(&sb[q * CHUNK + j0]) = kk;
      }
    }
    __syncthreads();
    const unsigned* sq = sb + w * CHUNK;
#pragma unroll
    for (int i = 0; i < NQ4; ++i)
      key[ch * NQ4 + i] = *reinterpret_cast<const uint4*>(&sq[i * 256 + lane * 4]);
    __syncthreads();
  }
  // reg r = ch*NQ4 + i holds global keys j = ch*CHUNK + i*256 + lane*4 + c.

  // ---- global max (f2o order-preserving) ----
  unsigned mk = 0u;
#pragma unroll
  for (int r = 0; r < NV4; ++r) {
    unsigned a = key[r].x > key[r].y ? key[r].x : key[r].y;
    unsigned bb = key[r].z > key[r].w ? key[r].z : key[r].w;
    a = a > bb ? a : bb;
    mk = a > mk ? a : mk;
  }
  for (int off = 32; off > 0; off >>= 1) {
    unsigned o = (unsigned)__shfl_xor((int)mk, off, 64);
    mk = o > mk ? o : mk;
  }
  const float mx = o2f(mk);

  // ---- radix select: kth-largest key (k=128) ----
  unsigned* hw = hist[w];
  unsigned kth = 0u, mask = 0u;
  int rem = KSEL;
#pragma unroll
  for (int shift = 24; shift >= 0; shift -= 8) {
#pragma unroll
    for (int i = 0; i < 4; ++i) hw[lane + i * 64] = 0u;
    if (shift == 24) {
#pragma unroll
      for (int r = 0; r < NV4; ++r) {
        atomicAdd(&hw[key[r].x >> 24], 1u); atomicAdd(&hw[key[r].y >> 24], 1u);
        atomicAdd(&hw[key[r].z >> 24], 1u); atomicAdd(&hw[key[r].w >> 24], 1u);
      }
    } else {
#pragma unroll
      for (int r = 0; r < NV4; ++r) {
        if ((key[r].x & mask) == kth) atomicAdd(&hw[(key[r].x >> shift) & 255u], 1u);
        if ((key[r].y & mask) == kth) atomicAdd(&hw[(key[r].y >> shift) & 255u], 1u);
        if ((key[r].z & mask) == kth) atomicAdd(&hw[(key[r].z >> shift) & 255u], 1u);
        if ((key[r].w & mask) == kth) atomicAdd(&hw[(key[r].w >> shift) & 255u], 1u);
      }
    }
    // wave suffix-scan over 256 bins, 4 bins/lane descending
    int v[4], loc = 0;
#pragma unroll
    for (int i = 0; i < 4; ++i) { v[i] = (int)hw[255 - (lane * 4 + i)]; loc += v[i]; }
    int incl = loc;
#pragma unroll
    for (int off = 1; off < 64; off <<= 1) {
      int t = __shfl_up(incl, off, 64);
      if (lane >= off) incl += t;
    }
    int c = incl - loc;  // count in bins strictly above this lane's bins
    int selidx = -1, selexcl = 0;
#pragma unroll
    for (int i = 0; i < 4; ++i) {
      if (selidx < 0 && rem > c && rem <= c + v[i]) {
        selidx = 255 - (lane * 4 + i); selexcl = c;
      }
      c += v[i];
    }
    unsigned long long vote = __ballot(selidx >= 0);
    int src = __ffsll((long long)vote) - 1;
    selidx = __shfl(selidx, src, 64);
    selexcl = __shfl(selexcl, src, 64);
    rem -= selexcl;
    kth |= ((unsigned)selidx << shift);
    mask |= (0xFFu << shift);
  }
  const int need_eq = rem;   // boundary slots among ==kth, lowest index first

  // ---- compact: exact j-ascending tie ranking via 4-ballot ranks ----
  int selbase = 0, eqbase = 0;
  float lz = 0.f;
#pragma unroll
  for (int r = 0; r < NV4; ++r) {
    const int regj = (r / NQ4) * CHUNK + (r % NQ4) * 256;
    unsigned uu[4] = {key[r].x, key[r].y, key[r].z, key[r].w};
    bool eqf[4], self[4];
    unsigned long long beq[4];
#pragma unroll
    for (int c = 0; c < 4; ++c) { eqf[c] = (uu[c] == kth); beq[c] = __ballot(eqf[c]); }
    int eqlt = 0;
#pragma unroll
    for (int c = 0; c < 4; ++c) eqlt += __popcll(beq[c] & lanelt);
    int eqown = 0;
#pragma unroll
    for (int c = 0; c < 4; ++c) {
      self[c] = (uu[c] > kth) || (eqf[c] && (eqbase + eqlt + eqown) < need_eq);
      eqown += eqf[c] ? 1 : 0;
    }
    unsigned long long bsel[4];
#pragma unroll
    for (int c = 0; c < 4; ++c) bsel[c] = __ballot(self[c]);
    int sellt = 0;
#pragma unroll
    for (int c = 0; c < 4; ++c) sellt += __popcll(bsel[c] & lanelt);
    int selown = 0;
#pragma unroll
    for (int c = 0; c < 4; ++c) {
      if (self[c]) {
        int pos = selbase + sellt + selown;
        float e = expf(o2f(uu[c]) - mx);
        idxb[w][pos] = regj + lane * 4 + c;
        wb[w][pos] = e;
        lz += e;
      }
      selown += self[c] ? 1 : 0;
    }
#pragma unroll
    for (int c = 0; c < 4; ++c) { eqbase += __popcll(beq[c]); selbase += __popcll(bsel[c]); }
  }
  for (int off = 32; off > 0; off >>= 1) lz += __shfl_xor(lz, off, 64);
  const float rz = 1.f / lz;

  // ---- gather V (per wave, lane = dim) ----
  if (lane < HD) {
    float acc = 0.f;
#pragma unroll 4
    for (int p = 0; p < KSEL; ++p) {
      acc = fmaf(wb[w][p], V[((size_t)(b * N + idxb[w][p])) * TD + h * HD + lane], acc);
    }
    O[((size_t)(b * N + q0 + w)) * TD + h * HD + lane] = acc * rz;
  }
}

// out[b, t, n0+nl] = O[b, n0+nl, :] . ow[:, t] + ob[t]; 64-token LDS tile.
#define TOK 64
__global__ __launch_bounds__(256) void oproj_kernel(
    const float* __restrict__ O, const float* __restrict__ ow,
    const float* __restrict__ ob, float* __restrict__ out, int N) {
  __shared__ float otile[TOK][TD + 1];
  const int tid = threadIdx.x;
  const int nt = N / TOK;
  const int b = blockIdx.x / nt;
  const int n0 = (blockIdx.x % nt) * TOK;
  const float* obase = O + ((size_t)(b * N + n0)) * TD;
  for (int idx = tid * 4; idx < TOK * TD; idx += 1024) {
    float4 v = *reinterpret_cast<const float4*>(obase + idx);
    int r = idx / TD, c = idx - r * TD;
    otile[r][c] = v.x; otile[r][c + 1] = v.y; otile[r][c + 2] = v.z; otile[r][c + 3] = v.w;
  }
  __syncthreads();
  const int nl = tid >> 2;            // 0..63 token
  const int ts = (tid & 3) * 48;      // output-channel group
  float acc[48];
#pragma unroll
  for (int i = 0; i < 48; ++i) acc[i] = 0.f;
  for (int c = 0; c < TD; ++c) {
    float oval = otile[nl][c];
    const float* wr = ow + c * TD + ts;
#pragma unroll
    for (int i = 0; i < 48; ++i) acc[i] = fmaf(oval, wr[i], acc[i]);
  }
#pragma unroll
  for (int i = 0; i < 48; ++i) {
    int t = ts + i;
    out[((size_t)(b * TD + t)) * N + n0 + nl] = acc[i] + ob[t];
  }
}

extern "C" void kernel_launch(void* const* d_in, const int* in_sizes, int n_in,
                              void* d_out, int out_size, void* d_ws, size_t ws_size,
                              hipStream_t stream) {
  const int B = 2;
  const int Cs[3] = {64, 128, 192};
  const int Hs[3] = {64, 32, 16};
  const size_t out_off[3] = {0,
                             (size_t)2 * TD * 64 * 64,
                             (size_t)2 * TD * 64 * 64 + (size_t)2 * TD * 32 * 32};

  float* ws = (float*)d_ws;
  float* pe = ws;                                 // 4096*192
  float* Q = pe + (size_t)4096 * TD;              // 2*4096*192
  float* Kt = Q + (size_t)B * 4096 * TD;
  float* V = Kt + (size_t)B * 4096 * TD;
  float* Obuf = V + (size_t)B * 4096 * TD;

  for (int lvl = 0; lvl < 3; ++lvl) {
    int C = Cs[lvl], H = Hs[lvl], W = H, N = H * W;
    const float* feat1 = (const float*)d_in[lvl * 2 + 0];
    const float* feat2 = (const float*)d_in[lvl * 2 + 1];
    const float* qw = (const float*)d_in[6 + lvl * 8 + 0];
    const float* qb = (const float*)d_in[6 + lvl * 8 + 1];
    const float* kw = (const float*)d_in[6 + lvl * 8 + 2];
    const float* kb = (const float*)d_in[6 + lvl * 8 + 3];
    const float* vw = (const float*)d_in[6 + lvl * 8 + 4];
    const float* vb = (const float*)d_in[6 + lvl * 8 + 5];
    const float* ow = (const float*)d_in[6 + lvl * 8 + 6];
    const float* ob = (const float*)d_in[6 + lvl * 8 + 7];

    pe_kernel<<<N, TD, 0, stream>>>(pe, W);
    qkv_kernel<<<B * N, TD, 0, stream>>>(feat1, feat2, qw, qb, kw, kb, vw, vb, pe, Q, Kt, V, C, N);
    int chunk = N > 2048 ? 2048 : N;
    size_t shm = (size_t)QB * chunk * sizeof(unsigned);
    int nblk = B * 4 * (N / QB);
    if (N == 4096)      attn_kernel<4096><<<nblk, 256, shm, stream>>>(Q, Kt, V, Obuf);
    else if (N == 1024) attn_kernel<1024><<<nblk, 256, shm, stream>>>(Q, Kt, V, Obuf);
    else                attn_kernel<256><<<nblk, 256, shm, stream>>>(Q, Kt, V, Obuf);
    oproj_kernel<<<B * (N / TOK), 256, 0, stream>>>(Obuf, ow, ob, (float*)d_out + out_off[lvl], N);
  }
}

// Round 5
// 4358.491 us; speedup vs baseline: 1.0069x; 1.0069x over previous
//
#include <hip/hip_runtime.h>
#include <math.h>

#define TD 192
#define HD 48
#define KSEL 128
#define QB 4

// Map float to orderable unsigned: a > b (float) <=> f2o(a) > f2o(b)
__device__ __forceinline__ unsigned f2o(float f) {
  unsigned u = __float_as_uint(f);
  return (u & 0x80000000u) ? ~u : (u | 0x80000000u);
}
__device__ __forceinline__ float o2f(unsigned u) {
  unsigned v = (u & 0x80000000u) ? (u & 0x7fffffffu) : ~u;
  return __uint_as_float(v);
}

// 2D sinusoidal positional encoding, matches reference _pos_enc.
__global__ void pe_kernel(float* __restrict__ pe, int W) {
  int n = blockIdx.x;
  int t = threadIdx.x;                      // 0..191
  const float c = -0.09594104554885301f;    // -ln(10000)/96
  float val;
  if (t < 96) {
    float dv = expf((float)t * c);
    val = sinf((float)(n % W) * dv);
  } else {
    float dv = expf((float)(t - 96) * c);
    val = cosf((float)(n / W) * dv);
  }
  pe[n * TD + t] = val;
}

// Q = f1@qw+qb+pe (row-major [b][n][td])
// Kt = transpose of (f2@kw+kb+pe) -> [b][h][d][N]
// V = f2@vw+vb (row-major)
__global__ void qkv_kernel(const float* __restrict__ feat1, const float* __restrict__ feat2,
                           const float* __restrict__ qw, const float* __restrict__ qb,
                           const float* __restrict__ kw, const float* __restrict__ kb,
                           const float* __restrict__ vw, const float* __restrict__ vb,
                           const float* __restrict__ pe,
                           float* __restrict__ Q, float* __restrict__ Kt, float* __restrict__ V,
                           int C, int N) {
  int t = threadIdx.x;            // 0..191
  int bn = blockIdx.x;            // b*N + n
  int b = bn / N, n = bn - b * N;
  const float* f1 = feat1 + (size_t)b * C * N + n;
  const float* f2 = feat2 + (size_t)b * C * N + n;
  float q = 0.f, k = 0.f, v = 0.f;
  for (int c = 0; c < C; ++c) {
    float a1 = f1[(size_t)c * N];
    float a2 = f2[(size_t)c * N];
    q = fmaf(a1, qw[c * TD + t], q);
    k = fmaf(a2, kw[c * TD + t], k);
    v = fmaf(a2, vw[c * TD + t], v);
  }
  float p = pe[n * TD + t];
  size_t o = (size_t)bn * TD + t;
  Q[o] = q + qb[t] + p;
  V[o] = v + vb[t];
  int h = t / HD, d = t - h * HD;
  Kt[(((size_t)b * 4 + h) * HD + d) * N + n] = k + kb[t] + p;
}

// One block per (b, h, group of QB=4 queries). Score GEMM is block-cooperative
// through a CHUNK-key LDS window (32KB max) so 3 blocks/CU fit; wave w keeps
// query w's full key set in registers (uint4 vectorized handoff; ALL indices
// compile-time constant — rule #20: runtime-indexed arrays go to scratch),
// then radix-select top-128 with exact lowest-index tie ranking, softmax,
// V gather.
template <int N>
__global__ __launch_bounds__(256, 3) void attn_kernel(
    const float* __restrict__ Q, const float* __restrict__ Kt, const float* __restrict__ V,
    float* __restrict__ O) {
  constexpr int CHUNK = (N > 2048) ? 2048 : N;   // LDS staging window
  constexpr int NCH = N / CHUNK;
  constexpr int NQ4 = CHUNK / 256;               // uint4 regs per lane per chunk
  constexpr int NV4 = N / 256;                   // total uint4 regs per lane
  extern __shared__ unsigned sb[];               // QB * CHUNK keys
  __shared__ float qv[QB][HD];
  __shared__ unsigned hist[4][256];
  __shared__ int idxb[4][KSEL];
  __shared__ float wb[4][KSEL];

  const int tid = threadIdx.x;
  const int nq = N / QB;
  const int qg = blockIdx.x % nq;
  const int h = (blockIdx.x / nq) & 3;
  const int b = blockIdx.x / (4 * nq);
  const int q0 = qg * QB;
  const float scale = 0.14433756729740643f;  // 1/sqrt(48)

  if (tid < QB * HD) {
    int q = tid / HD, d = tid - q * HD;
    qv[q][d] = Q[((size_t)(b * N + q0 + q)) * TD + h * HD + d];
  }
  __syncthreads();

  const int w = tid >> 6, lane = tid & 63;
  const unsigned long long lanelt = (1ull << lane) - 1ull;
  const float* kt = Kt + ((size_t)(b * 4 + h) * HD) * N;
  uint4 key[NV4];

  // ---- chunked score GEMM -> LDS -> per-wave registers ----
  // FULLY UNROLLED chunk loop: key[] indices must be compile-time constants.
#pragma unroll
  for (int ch = 0; ch < NCH; ++ch) {
    const int jbase = ch * CHUNK;
    for (int j0 = tid * 4; j0 < CHUNK; j0 += 1024) {
      float4 acc[QB];
#pragma unroll
      for (int q = 0; q < QB; ++q) acc[q] = make_float4(0.f, 0.f, 0.f, 0.f);
#pragma unroll
      for (int d4 = 0; d4 < HD; d4 += 4) {
        float4 k0 = *reinterpret_cast<const float4*>(kt + (size_t)(d4 + 0) * N + jbase + j0);
        float4 k1 = *reinterpret_cast<const float4*>(kt + (size_t)(d4 + 1) * N + jbase + j0);
        float4 k2 = *reinterpret_cast<const float4*>(kt + (size_t)(d4 + 2) * N + jbase + j0);
        float4 k3 = *reinterpret_cast<const float4*>(kt + (size_t)(d4 + 3) * N + jbase + j0);
#pragma unroll
        for (int q = 0; q < QB; ++q) {
          float4 qq = *reinterpret_cast<const float4*>(&qv[q][d4]);
          acc[q].x = fmaf(qq.x, k0.x, acc[q].x); acc[q].x = fmaf(qq.y, k1.x, acc[q].x);
          acc[q].x = fmaf(qq.z, k2.x, acc[q].x); acc[q].x = fmaf(qq.w, k3.x, acc[q].x);
          acc[q].y = fmaf(qq.x, k0.y, acc[q].y); acc[q].y = fmaf(qq.y, k1.y, acc[q].y);
          acc[q].y = fmaf(qq.z, k2.y, acc[q].y); acc[q].y = fmaf(qq.w, k3.y, acc[q].y);
          acc[q].z = fmaf(qq.x, k0.z, acc[q].z); acc[q].z = fmaf(qq.y, k1.z, acc[q].z);
          acc[q].z = fmaf(qq.z, k2.z, acc[q].z); acc[q].z = fmaf(qq.w, k3.z, acc[q].z);
          acc[q].w = fmaf(qq.x, k0.w, acc[q].w); acc[q].w = fmaf(qq.y, k1.w, acc[q].w);
          acc[q].w = fmaf(qq.z, k2.w, acc[q].w); acc[q].w = fmaf(qq.w, k3.w, acc[q].w);
        }
      }
#pragma unroll
      for (int q = 0; q < QB; ++q) {
        uint4 kk;
        kk.x = f2o(acc[q].x * scale); kk.y = f2o(acc[q].y * scale);
        kk.z = f2o(acc[q].z * scale); kk.w = f2o(acc[q].w * scale);
        *reinterpret_cast<uint4*>(&sb[q * CHUNK + j0]) = kk;
      }
    }
    __syncthreads();
    const unsigned* sq = sb + w * CHUNK;
#pragma unroll
    for (int i = 0; i < NQ4; ++i)
      key[ch * NQ4 + i] = *reinterpret_cast<const uint4*>(&sq[i * 256 + lane * 4]);
    __syncthreads();
  }
  // reg r = ch*NQ4 + i holds global keys j = ch*CHUNK + i*256 + lane*4 + c.

  // ---- global max (f2o order-preserving) ----
  unsigned mk = 0u;
#pragma unroll
  for (int r = 0; r < NV4; ++r) {
    unsigned a = key[r].x > key[r].y ? key[r].x : key[r].y;
    unsigned bb = key[r].z > key[r].w ? key[r].z : key[r].w;
    a = a > bb ? a : bb;
    mk = a > mk ? a : mk;
  }
  for (int off = 32; off > 0; off >>= 1) {
    unsigned o = (unsigned)__shfl_xor((int)mk, off, 64);
    mk = o > mk ? o : mk;
  }
  const float mx = o2f(mk);

  // ---- radix select: kth-largest key (k=128) ----
  unsigned* hw = hist[w];
  unsigned kth = 0u, mask = 0u;
  int rem = KSEL;
#pragma unroll
  for (int shift = 24; shift >= 0; shift -= 8) {
#pragma unroll
    for (int i = 0; i < 4; ++i) hw[lane + i * 64] = 0u;
    if (shift == 24) {
#pragma unroll
      for (int r = 0; r < NV4; ++r) {
        atomicAdd(&hw[key[r].x >> 24], 1u); atomicAdd(&hw[key[r].y >> 24], 1u);
        atomicAdd(&hw[key[r].z >> 24], 1u); atomicAdd(&hw[key[r].w >> 24], 1u);
      }
    } else {
#pragma unroll
      for (int r = 0; r < NV4; ++r) {
        if ((key[r].x & mask) == kth) atomicAdd(&hw[(key[r].x >> shift) & 255u], 1u);
        if ((key[r].y & mask) == kth) atomicAdd(&hw[(key[r].y >> shift) & 255u], 1u);
        if ((key[r].z & mask) == kth) atomicAdd(&hw[(key[r].z >> shift) & 255u], 1u);
        if ((key[r].w & mask) == kth) atomicAdd(&hw[(key[r].w >> shift) & 255u], 1u);
      }
    }
    // wave suffix-scan over 256 bins, 4 bins/lane descending
    int v[4], loc = 0;
#pragma unroll
    for (int i = 0; i < 4; ++i) { v[i] = (int)hw[255 - (lane * 4 + i)]; loc += v[i]; }
    int incl = loc;
#pragma unroll
    for (int off = 1; off < 64; off <<= 1) {
      int t = __shfl_up(incl, off, 64);
      if (lane >= off) incl += t;
    }
    int c = incl - loc;  // count in bins strictly above this lane's bins
    int selidx = -1, selexcl = 0;
#pragma unroll
    for (int i = 0; i < 4; ++i) {
      if (selidx < 0 && rem > c && rem <= c + v[i]) {
        selidx = 255 - (lane * 4 + i); selexcl = c;
      }
      c += v[i];
    }
    unsigned long long vote = __ballot(selidx >= 0);
    int src = __ffsll((long long)vote) - 1;
    selidx = __shfl(selidx, src, 64);
    selexcl = __shfl(selexcl, src, 64);
    rem -= selexcl;
    kth |= ((unsigned)selidx << shift);
    mask |= (0xFFu << shift);
  }
  const int need_eq = rem;   // boundary slots among ==kth, lowest index first

  // ---- compact: exact j-ascending tie ranking via 4-ballot ranks ----
  int selbase = 0, eqbase = 0;
  float lz = 0.f;
#pragma unroll
  for (int r = 0; r < NV4; ++r) {
    const int regj = (r / NQ4) * CHUNK + (r % NQ4) * 256;
    unsigned uu[4] = {key[r].x, key[r].y, key[r].z, key[r].w};
    bool eqf[4], self[4];
    unsigned long long beq[4];
#pragma unroll
    for (int c = 0; c < 4; ++c) { eqf[c] = (uu[c] == kth); beq[c] = __ballot(eqf[c]); }
    int eqlt = 0;
#pragma unroll
    for (int c = 0; c < 4; ++c) eqlt += __popcll(beq[c] & lanelt);
    int eqown = 0;
#pragma unroll
    for (int c = 0; c < 4; ++c) {
      self[c] = (uu[c] > kth) || (eqf[c] && (eqbase + eqlt + eqown) < need_eq);
      eqown += eqf[c] ? 1 : 0;
    }
    unsigned long long bsel[4];
#pragma unroll
    for (int c = 0; c < 4; ++c) bsel[c] = __ballot(self[c]);
    int sellt = 0;
#pragma unroll
    for (int c = 0; c < 4; ++c) sellt += __popcll(bsel[c] & lanelt);
    int selown = 0;
#pragma unroll
    for (int c = 0; c < 4; ++c) {
      if (self[c]) {
        int pos = selbase + sellt + selown;
        float e = expf(o2f(uu[c]) - mx);
        idxb[w][pos] = regj + lane * 4 + c;
        wb[w][pos] = e;
        lz += e;
      }
      selown += self[c] ? 1 : 0;
    }
#pragma unroll
    for (int c = 0; c < 4; ++c) { eqbase += __popcll(beq[c]); selbase += __popcll(bsel[c]); }
  }
  for (int off = 32; off > 0; off >>= 1) lz += __shfl_xor(lz, off, 64);
  const float rz = 1.f / lz;

  // ---- gather V (per wave, lane = dim) ----
  if (lane < HD) {
    float acc = 0.f;
#pragma unroll 4
    for (int p = 0; p < KSEL; ++p) {
      acc = fmaf(wb[w][p], V[((size_t)(b * N + idxb[w][p])) * TD + h * HD + lane], acc);
    }
    O[((size_t)(b * N + q0 + w)) * TD + h * HD + lane] = acc * rz;
  }
}

// out[b, t, n0+nl] = O[b, n0+nl, :] . ow[:, t] + ob[t]; 64-token LDS tile.
#define TOK 64
__global__ __launch_bounds__(256) void oproj_kernel(
    const float* __restrict__ O, const float* __restrict__ ow,
    const float* __restrict__ ob, float* __restrict__ out, int N) {
  __shared__ float otile[TOK][TD + 1];
  const int tid = threadIdx.x;
  const int nt = N / TOK;
  const int b = blockIdx.x / nt;
  const int n0 = (blockIdx.x % nt) * TOK;
  const float* obase = O + ((size_t)(b * N + n0)) * TD;
  for (int idx = tid * 4; idx < TOK * TD; idx += 1024) {
    float4 v = *reinterpret_cast<const float4*>(obase + idx);
    int r = idx / TD, c = idx - r * TD;
    otile[r][c] = v.x; otile[r][c + 1] = v.y; otile[r][c + 2] = v.z; otile[r][c + 3] = v.w;
  }
  __syncthreads();
  const int nl = tid >> 2;            // 0..63 token
  const int ts = (tid & 3) * 48;      // output-channel group
  float acc[48];
#pragma unroll
  for (int i = 0; i < 48; ++i) acc[i] = 0.f;
  for (int c = 0; c < TD; ++c) {
    float oval = otile[nl][c];
    const float* wr = ow + c * TD + ts;
#pragma unroll
    for (int i = 0; i < 48; ++i) acc[i] = fmaf(oval, wr[i], acc[i]);
  }
#pragma unroll
  for (int i = 0; i < 48; ++i) {
    int t = ts + i;
    out[((size_t)(b * TD + t)) * N + n0 + nl] = acc[i] + ob[t];
  }
}

extern "C" void kernel_launch(void* const* d_in, const int* in_sizes, int n_in,
                              void* d_out, int out_size, void* d_ws, size_t ws_size,
                              hipStream_t stream) {
  const int B = 2;
  const int Cs[3] = {64, 128, 192};
  const int Hs[3] = {64, 32, 16};
  const size_t out_off[3] = {0,
                             (size_t)2 * TD * 64 * 64,
                             (size_t)2 * TD * 64 * 64 + (size_t)2 * TD * 32 * 32};

  float* ws = (float*)d_ws;
  float* pe = ws;                                 // 4096*192
  float* Q = pe + (size_t)4096 * TD;              // 2*4096*192
  float* Kt = Q + (size_t)B * 4096 * TD;
  float* V = Kt + (size_t)B * 4096 * TD;
  float* Obuf = V + (size_t)B * 4096 * TD;

  for (int lvl = 0; lvl < 3; ++lvl) {
    int C = Cs[lvl], H = Hs[lvl], W = H, N = H * W;
    const float* feat1 = (const float*)d_in[lvl * 2 + 0];
    const float* feat2 = (const float*)d_in[lvl * 2 + 1];
    const float* qw = (const float*)d_in[6 + lvl * 8 + 0];
    const float* qb = (const float*)d_in[6 + lvl * 8 + 1];
    const float* kw = (const float*)d_in[6 + lvl * 8 + 2];
    const float* kb = (const float*)d_in[6 + lvl * 8 + 3];
    const float* vw = (const float*)d_in[6 + lvl * 8 + 4];
    const float* vb = (const float*)d_in[6 + lvl * 8 + 5];
    const float* ow = (const float*)d_in[6 + lvl * 8 + 6];
    const float* ob = (const float*)d_in[6 + lvl * 8 + 7];

    pe_kernel<<<N, TD, 0, stream>>>(pe, W);
    qkv_kernel<<<B * N, TD, 0, stream>>>(feat1, feat2, qw, qb, kw, kb, vw, vb, pe, Q, Kt, V, C, N);
    int chunk = N > 2048 ? 2048 : N;
    size_t shm = (size_t)QB * chunk * sizeof(unsigned);
    int nblk = B * 4 * (N / QB);
    if (N == 4096)      attn_kernel<4096><<<nblk, 256, shm, stream>>>(Q, Kt, V, Obuf);
    else if (N == 1024) attn_kernel<1024><<<nblk, 256, shm, stream>>>(Q, Kt, V, Obuf);
    else                attn_kernel<256><<<nblk, 256, shm, stream>>>(Q, Kt, V, Obuf);
    oproj_kernel<<<B * (N / TOK), 256, 0, stream>>>(Obuf, ow, ob, (float*)d_out + out_off[lvl], N);
  }
}

// Round 6
// 4147.147 us; speedup vs baseline: 1.0582x; 1.0510x over previous
//
#include <hip/hip_runtime.h>
#include <math.h>

#define TD 192
#define HD 48
#define KSEL 128
#define QB 4

// Map float to orderable unsigned: a > b (float) <=> f2o(a) > f2o(b)
__device__ __forceinline__ unsigned f2o(float f) {
  unsigned u = __float_as_uint(f);
  return (u & 0x80000000u) ? ~u : (u | 0x80000000u);
}
__device__ __forceinline__ float o2f(unsigned u) {
  unsigned v = (u & 0x80000000u) ? (u & 0x7fffffffu) : ~u;
  return __uint_as_float(v);
}

// 2D sinusoidal positional encoding, matches reference _pos_enc.
__global__ void pe_kernel(float* __restrict__ pe, int W) {
  int n = blockIdx.x;
  int t = threadIdx.x;                      // 0..191
  const float c = -0.09594104554885301f;    // -ln(10000)/96
  float val;
  if (t < 96) {
    float dv = expf((float)t * c);
    val = sinf((float)(n % W) * dv);
  } else {
    float dv = expf((float)(t - 96) * c);
    val = cosf((float)(n / W) * dv);
  }
  pe[n * TD + t] = val;
}

// Q = f1@qw+qb+pe (row-major [b][n][td])
// Kt = transpose of (f2@kw+kb+pe) -> [b][h][d][N]
// V = f2@vw+vb (row-major)
__global__ void qkv_kernel(const float* __restrict__ feat1, const float* __restrict__ feat2,
                           const float* __restrict__ qw, const float* __restrict__ qb,
                           const float* __restrict__ kw, const float* __restrict__ kb,
                           const float* __restrict__ vw, const float* __restrict__ vb,
                           const float* __restrict__ pe,
                           float* __restrict__ Q, float* __restrict__ Kt, float* __restrict__ V,
                           int C, int N) {
  int t = threadIdx.x;            // 0..191
  int bn = blockIdx.x;            // b*N + n
  int b = bn / N, n = bn - b * N;
  const float* f1 = feat1 + (size_t)b * C * N + n;
  const float* f2 = feat2 + (size_t)b * C * N + n;
  float q = 0.f, k = 0.f, v = 0.f;
  for (int c = 0; c < C; ++c) {
    float a1 = f1[(size_t)c * N];
    float a2 = f2[(size_t)c * N];
    q = fmaf(a1, qw[c * TD + t], q);
    k = fmaf(a2, kw[c * TD + t], k);
    v = fmaf(a2, vw[c * TD + t], v);
  }
  float p = pe[n * TD + t];
  size_t o = (size_t)bn * TD + t;
  Q[o] = q + qb[t] + p;
  V[o] = v + vb[t];
  int h = t / HD, d = t - h * HD;
  Kt[(((size_t)b * 4 + h) * HD + d) * N + n] = k + kb[t] + p;
}

// ---- named-register key set machinery (rule #20: arrays with any runtime
// indexing go to scratch; named uint4 scalars CANNOT be demoted) ----
#define KAPPLY(OP, A) \
  OP(0, A) OP(1, A) OP(2, A) OP(3, A) OP(4, A) OP(5, A) OP(6, A) OP(7, A) \
  OP(8, A) OP(9, A) OP(10, A) OP(11, A) OP(12, A) OP(13, A) OP(14, A) OP(15, A)

// One block per (b, h, group of QB=4 queries). Score GEMM is block-cooperative
// through a CHUNK-key LDS window; wave w keeps query w's full key set in 16
// NAMED uint4 registers, then radix-selects top-128 with exact lowest-index
// tie ranking, softmax, V gather.
template <int N>
__global__ __launch_bounds__(256, 3) void attn_kernel(
    const float* __restrict__ Q, const float* __restrict__ Kt, const float* __restrict__ V,
    float* __restrict__ O) {
  constexpr int CHUNK = (N > 2048) ? 2048 : N;   // LDS staging window
  constexpr int NCH = N / CHUNK;                 // 1 or 2
  constexpr int NQ4 = CHUNK / 256;               // uint4 regs per lane per chunk
  constexpr int NV4 = N / 256;                   // total uint4 regs per lane (<=16)
  extern __shared__ unsigned sb[];               // QB * CHUNK keys
  __shared__ float qv[QB][HD];
  __shared__ unsigned hist[4][256];
  __shared__ int idxb[4][KSEL];
  __shared__ float wb[4][KSEL];

  const int tid = threadIdx.x;
  const int nq = N / QB;
  const int qg = blockIdx.x % nq;
  const int h = (blockIdx.x / nq) & 3;
  const int b = blockIdx.x / (4 * nq);
  const int q0 = qg * QB;
  const float scale = 0.14433756729740643f;  // 1/sqrt(48)

  if (tid < QB * HD) {
    int q = tid / HD, d = tid - q * HD;
    qv[q][d] = Q[((size_t)(b * N + q0 + q)) * TD + h * HD + d];
  }
  __syncthreads();

  const int w = tid >> 6, lane = tid & 63;
  const unsigned long long lanelt = (1ull << lane) - 1ull;
  const float* kt = Kt + ((size_t)(b * 4 + h) * HD) * N;

  uint4 k0 = make_uint4(0,0,0,0), k1 = k0, k2 = k0, k3 = k0, k4 = k0, k5 = k0,
        k6 = k0, k7 = k0, k8 = k0, k9 = k0, k10 = k0, k11 = k0, k12 = k0,
        k13 = k0, k14 = k0, k15 = k0;

#define LOAD_KEY(i, CH) \
  if constexpr ((i) >= (CH) * NQ4 && (i) < ((CH) + 1) * NQ4 && (i) < NV4) { \
    k##i = *reinterpret_cast<const uint4*>(&sq[((i) - (CH) * NQ4) * 256 + lane * 4]); }

#define GEMM_CHUNK(CH) { \
    const int jbase = (CH) * CHUNK; \
    for (int j0 = tid * 4; j0 < CHUNK; j0 += 1024) { \
      float4 acc[QB]; \
      _Pragma("unroll") for (int q = 0; q < QB; ++q) acc[q] = make_float4(0.f, 0.f, 0.f, 0.f); \
      _Pragma("unroll") for (int d4 = 0; d4 < HD; d4 += 4) { \
        float4 kk0 = *reinterpret_cast<const float4*>(kt + (size_t)(d4 + 0) * N + jbase + j0); \
        float4 kk1 = *reinterpret_cast<const float4*>(kt + (size_t)(d4 + 1) * N + jbase + j0); \
        float4 kk2 = *reinterpret_cast<const float4*>(kt + (size_t)(d4 + 2) * N + jbase + j0); \
        float4 kk3 = *reinterpret_cast<const float4*>(kt + (size_t)(d4 + 3) * N + jbase + j0); \
        _Pragma("unroll") for (int q = 0; q < QB; ++q) { \
          float4 qq = *reinterpret_cast<const float4*>(&qv[q][d4]); \
          acc[q].x = fmaf(qq.x, kk0.x, acc[q].x); acc[q].x = fmaf(qq.y, kk1.x, acc[q].x); \
          acc[q].x = fmaf(qq.z, kk2.x, acc[q].x); acc[q].x = fmaf(qq.w, kk3.x, acc[q].x); \
          acc[q].y = fmaf(qq.x, kk0.y, acc[q].y); acc[q].y = fmaf(qq.y, kk1.y, acc[q].y); \
          acc[q].y = fmaf(qq.z, kk2.y, acc[q].y); acc[q].y = fmaf(qq.w, kk3.y, acc[q].y); \
          acc[q].z = fmaf(qq.x, kk0.z, acc[q].z); acc[q].z = fmaf(qq.y, kk1.z, acc[q].z); \
          acc[q].z = fmaf(qq.z, kk2.z, acc[q].z); acc[q].z = fmaf(qq.w, kk3.z, acc[q].z); \
          acc[q].w = fmaf(qq.x, kk0.w, acc[q].w); acc[q].w = fmaf(qq.y, kk1.w, acc[q].w); \
          acc[q].w = fmaf(qq.z, kk2.w, acc[q].w); acc[q].w = fmaf(qq.w, kk3.w, acc[q].w); \
        } \
      } \
      _Pragma("unroll") for (int q = 0; q < QB; ++q) { \
        uint4 kk; \
        kk.x = f2o(acc[q].x * scale); kk.y = f2o(acc[q].y * scale); \
        kk.z = f2o(acc[q].z * scale); kk.w = f2o(acc[q].w * scale); \
        *reinterpret_cast<uint4*>(&sb[q * CHUNK + j0]) = kk; \
      } \
    } \
    __syncthreads(); \
    { const unsigned* sq = sb + w * CHUNK; KAPPLY(LOAD_KEY, CH) } \
    __syncthreads(); }

  GEMM_CHUNK(0)
  if constexpr (NCH > 1) { GEMM_CHUNK(1) }
  // reg i holds global keys j = (i/NQ4)*CHUNK + (i%NQ4)*256 + lane*4 + c.

  // ---- global max (f2o order-preserving) ----
  unsigned mk = 0u;
#define MAXK(i, A) if constexpr ((i) < NV4) { \
    unsigned a_ = k##i.x > k##i.y ? k##i.x : k##i.y; \
    unsigned b_ = k##i.z > k##i.w ? k##i.z : k##i.w; \
    a_ = a_ > b_ ? a_ : b_; mk = a_ > mk ? a_ : mk; }
  KAPPLY(MAXK, 0)
  for (int off = 32; off > 0; off >>= 1) {
    unsigned o = (unsigned)__shfl_xor((int)mk, off, 64);
    mk = o > mk ? o : mk;
  }
  const float mx = o2f(mk);

  // ---- radix select: kth-largest key (k=128) ----
  unsigned* hw = hist[w];
  unsigned kth = 0u, mask = 0u;
  int rem = KSEL;
#define HISTK(i, A) if constexpr ((i) < NV4) { \
    if ((k##i.x & mask) == kth) atomicAdd(&hw[(k##i.x >> shift) & 255u], 1u); \
    if ((k##i.y & mask) == kth) atomicAdd(&hw[(k##i.y >> shift) & 255u], 1u); \
    if ((k##i.z & mask) == kth) atomicAdd(&hw[(k##i.z >> shift) & 255u], 1u); \
    if ((k##i.w & mask) == kth) atomicAdd(&hw[(k##i.w >> shift) & 255u], 1u); }
  for (int shift = 24; shift >= 0; shift -= 8) {
#pragma unroll
    for (int i = 0; i < 4; ++i) hw[lane + i * 64] = 0u;
    KAPPLY(HISTK, 0)
    // wave suffix-scan over 256 bins, 4 bins/lane descending
    int v[4], loc = 0;
#pragma unroll
    for (int i = 0; i < 4; ++i) { v[i] = (int)hw[255 - (lane * 4 + i)]; loc += v[i]; }
    int incl = loc;
#pragma unroll
    for (int off = 1; off < 64; off <<= 1) {
      int t = __shfl_up(incl, off, 64);
      if (lane >= off) incl += t;
    }
    int c = incl - loc;  // count in bins strictly above this lane's bins
    int selidx = -1, selexcl = 0;
#pragma unroll
    for (int i = 0; i < 4; ++i) {
      if (selidx < 0 && rem > c && rem <= c + v[i]) {
        selidx = 255 - (lane * 4 + i); selexcl = c;
      }
      c += v[i];
    }
    unsigned long long vote = __ballot(selidx >= 0);
    int src = __ffsll((long long)vote) - 1;
    selidx = __shfl(selidx, src, 64);
    selexcl = __shfl(selexcl, src, 64);
    rem -= selexcl;
    kth |= ((unsigned)selidx << shift);
    mask |= (0xFFu << shift);
  }
  const int need_eq = rem;   // boundary slots among ==kth, lowest index first

  // ---- compact: exact j-ascending tie ranking via ballot ranks ----
  int selbase = 0, eqbase = 0;
  float lz = 0.f;
#define COMPACT_K(i, A) if constexpr ((i) < NV4) { \
    constexpr int regj = ((i) / NQ4) * CHUNK + ((i) % NQ4) * 256; \
    const unsigned u0 = k##i.x, u1 = k##i.y, u2 = k##i.z, u3 = k##i.w; \
    const bool e0 = (u0 == kth), e1 = (u1 == kth), e2 = (u2 == kth), e3 = (u3 == kth); \
    const unsigned long long b0 = __ballot(e0), b1 = __ballot(e1), b2 = __ballot(e2), b3 = __ballot(e3); \
    const int eqlt = __popcll(b0 & lanelt) + __popcll(b1 & lanelt) + __popcll(b2 & lanelt) + __popcll(b3 & lanelt); \
    int eo = 0; \
    const bool s0 = (u0 > kth) || (e0 && (eqbase + eqlt + eo) < need_eq); eo += e0 ? 1 : 0; \
    const bool s1 = (u1 > kth) || (e1 && (eqbase + eqlt + eo) < need_eq); eo += e1 ? 1 : 0; \
    const bool s2 = (u2 > kth) || (e2 && (eqbase + eqlt + eo) < need_eq); eo += e2 ? 1 : 0; \
    const bool s3 = (u3 > kth) || (e3 && (eqbase + eqlt + eo) < need_eq); eo += e3 ? 1 : 0; \
    const unsigned long long c0 = __ballot(s0), c1 = __ballot(s1), c2 = __ballot(s2), c3 = __ballot(s3); \
    const int sellt = __popcll(c0 & lanelt) + __popcll(c1 & lanelt) + __popcll(c2 & lanelt) + __popcll(c3 & lanelt); \
    int so = 0; \
    if (s0) { int pos = selbase + sellt + so; float e = expf(o2f(u0) - mx); idxb[w][pos] = regj + lane * 4 + 0; wb[w][pos] = e; lz += e; } so += s0 ? 1 : 0; \
    if (s1) { int pos = selbase + sellt + so; float e = expf(o2f(u1) - mx); idxb[w][pos] = regj + lane * 4 + 1; wb[w][pos] = e; lz += e; } so += s1 ? 1 : 0; \
    if (s2) { int pos = selbase + sellt + so; float e = expf(o2f(u2) - mx); idxb[w][pos] = regj + lane * 4 + 2; wb[w][pos] = e; lz += e; } so += s2 ? 1 : 0; \
    if (s3) { int pos = selbase + sellt + so; float e = expf(o2f(u3) - mx); idxb[w][pos] = regj + lane * 4 + 3; wb[w][pos] = e; lz += e; } so += s3 ? 1 : 0; \
    eqbase += __popcll(b0) + __popcll(b1) + __popcll(b2) + __popcll(b3); \
    selbase += __popcll(c0) + __popcll(c1) + __popcll(c2) + __popcll(c3); }
  KAPPLY(COMPACT_K, 0)
  for (int off = 32; off > 0; off >>= 1) lz += __shfl_xor(lz, off, 64);
  const float rz = 1.f / lz;

  // ---- gather V (per wave, lane = dim) ----
  if (lane < HD) {
    float acc = 0.f;
#pragma unroll 4
    for (int p = 0; p < KSEL; ++p) {
      acc = fmaf(wb[w][p], V[((size_t)(b * N + idxb[w][p])) * TD + h * HD + lane], acc);
    }
    O[((size_t)(b * N + q0 + w)) * TD + h * HD + lane] = acc * rz;
  }
}

// out[b, t, n0+nl] = O[b, n0+nl, :] . ow[:, t] + ob[t]; 64-token LDS tile.
#define TOK 64
__global__ __launch_bounds__(256) void oproj_kernel(
    const float* __restrict__ O, const float* __restrict__ ow,
    const float* __restrict__ ob, float* __restrict__ out, int N) {
  __shared__ float otile[TOK][TD + 1];
  const int tid = threadIdx.x;
  const int nt = N / TOK;
  const int b = blockIdx.x / nt;
  const int n0 = (blockIdx.x % nt) * TOK;
  const float* obase = O + ((size_t)(b * N + n0)) * TD;
  for (int idx = tid * 4; idx < TOK * TD; idx += 1024) {
    float4 v = *reinterpret_cast<const float4*>(obase + idx);
    int r = idx / TD, c = idx - r * TD;
    otile[r][c] = v.x; otile[r][c + 1] = v.y; otile[r][c + 2] = v.z; otile[r][c + 3] = v.w;
  }
  __syncthreads();
  const int nl = tid >> 2;            // 0..63 token
  const int ts = (tid & 3) * 48;      // output-channel group
  float acc[48];
#pragma unroll
  for (int i = 0; i < 48; ++i) acc[i] = 0.f;
  for (int c = 0; c < TD; ++c) {
    float oval = otile[nl][c];
    const float* wr = ow + c * TD + ts;
#pragma unroll
    for (int i = 0; i < 48; ++i) acc[i] = fmaf(oval, wr[i], acc[i]);
  }
#pragma unroll
  for (int i = 0; i < 48; ++i) {
    int t = ts + i;
    out[((size_t)(b * TD + t)) * N + n0 + nl] = acc[i] + ob[t];
  }
}

extern "C" void kernel_launch(void* const* d_in, const int* in_sizes, int n_in,
                              void* d_out, int out_size, void* d_ws, size_t ws_size,
                              hipStream_t stream) {
  const int B = 2;
  const int Cs[3] = {64, 128, 192};
  const int Hs[3] = {64, 32, 16};
  const size_t out_off[3] = {0,
                             (size_t)2 * TD * 64 * 64,
                             (size_t)2 * TD * 64 * 64 + (size_t)2 * TD * 32 * 32};

  float* ws = (float*)d_ws;
  float* pe = ws;                                 // 4096*192
  float* Q = pe + (size_t)4096 * TD;              // 2*4096*192
  float* Kt = Q + (size_t)B * 4096 * TD;
  float* V = Kt + (size_t)B * 4096 * TD;
  float* Obuf = V + (size_t)B * 4096 * TD;

  for (int lvl = 0; lvl < 3; ++lvl) {
    int C = Cs[lvl], H = Hs[lvl], W = H, N = H * W;
    const float* feat1 = (const float*)d_in[lvl * 2 + 0];
    const float* feat2 = (const float*)d_in[lvl * 2 + 1];
    const float* qw = (const float*)d_in[6 + lvl * 8 + 0];
    const float* qb = (const float*)d_in[6 + lvl * 8 + 1];
    const float* kw = (const float*)d_in[6 + lvl * 8 + 2];
    const float* kb = (const float*)d_in[6 + lvl * 8 + 3];
    const float* vw = (const float*)d_in[6 + lvl * 8 + 4];
    const float* vb = (const float*)d_in[6 + lvl * 8 + 5];
    const float* ow = (const float*)d_in[6 + lvl * 8 + 6];
    const float* ob = (const float*)d_in[6 + lvl * 8 + 7];

    pe_kernel<<<N, TD, 0, stream>>>(pe, W);
    qkv_kernel<<<B * N, TD, 0, stream>>>(feat1, feat2, qw, qb, kw, kb, vw, vb, pe, Q, Kt, V, C, N);
    int chunk = N > 2048 ? 2048 : N;
    size_t shm = (size_t)QB * chunk * sizeof(unsigned);
    int nblk = B * 4 * (N / QB);
    if (N == 4096)      attn_kernel<4096><<<nblk, 256, shm, stream>>>(Q, Kt, V, Obuf);
    else if (N == 1024) attn_kernel<1024><<<nblk, 256, shm, stream>>>(Q, Kt, V, Obuf);
    else                attn_kernel<256><<<nblk, 256, shm, stream>>>(Q, Kt, V, Obuf);
    oproj_kernel<<<B * (N / TOK), 256, 0, stream>>>(Obuf, ow, ob, (float*)d_out + out_off[lvl], N);
  }
}

// Round 7
// 2889.363 us; speedup vs baseline: 1.5188x; 1.4353x over previous
//
#include <hip/hip_runtime.h>
#include <math.h>

#define TD 192
#define HD 48
#define KSEL 128
#define QB 4

// Map float to orderable unsigned: a > b (float) <=> f2o(a) > f2o(b)
__device__ __forceinline__ unsigned f2o(float f) {
  unsigned u = __float_as_uint(f);
  return (u & 0x80000000u) ? ~u : (u | 0x80000000u);
}
__device__ __forceinline__ float o2f(unsigned u) {
  unsigned v = (u & 0x80000000u) ? (u & 0x7fffffffu) : ~u;
  return __uint_as_float(v);
}

// 2D sinusoidal positional encoding, matches reference _pos_enc.
__global__ void pe_kernel(float* __restrict__ pe, int W) {
  int n = blockIdx.x;
  int t = threadIdx.x;                      // 0..191
  const float c = -0.09594104554885301f;    // -ln(10000)/96
  float val;
  if (t < 96) {
    float dv = expf((float)t * c);
    val = sinf((float)(n % W) * dv);
  } else {
    float dv = expf((float)(t - 96) * c);
    val = cosf((float)(n / W) * dv);
  }
  pe[n * TD + t] = val;
}

// Q = f1@qw+qb+pe (row-major [b][n][td])
// Kt = transpose of (f2@kw+kb+pe) -> [b][h][d][N]
// V = f2@vw+vb (row-major)
__global__ void qkv_kernel(const float* __restrict__ feat1, const float* __restrict__ feat2,
                           const float* __restrict__ qw, const float* __restrict__ qb,
                           const float* __restrict__ kw, const float* __restrict__ kb,
                           const float* __restrict__ vw, const float* __restrict__ vb,
                           const float* __restrict__ pe,
                           float* __restrict__ Q, float* __restrict__ Kt, float* __restrict__ V,
                           int C, int N) {
  int t = threadIdx.x;            // 0..191
  int bn = blockIdx.x;            // b*N + n
  int b = bn / N, n = bn - b * N;
  const float* f1 = feat1 + (size_t)b * C * N + n;
  const float* f2 = feat2 + (size_t)b * C * N + n;
  float q = 0.f, k = 0.f, v = 0.f;
  for (int c = 0; c < C; ++c) {
    float a1 = f1[(size_t)c * N];
    float a2 = f2[(size_t)c * N];
    q = fmaf(a1, qw[c * TD + t], q);
    k = fmaf(a2, kw[c * TD + t], k);
    v = fmaf(a2, vw[c * TD + t], v);
  }
  float p = pe[n * TD + t];
  size_t o = (size_t)bn * TD + t;
  Q[o] = q + qb[t] + p;
  V[o] = v + vb[t];
  int h = t / HD, d = t - h * HD;
  Kt[(((size_t)b * 4 + h) * HD + d) * N + n] = k + kb[t] + p;
}

// ---- named-register key set machinery ----
#define KAPPLY(OP, A) \
  OP(0, A) OP(1, A) OP(2, A) OP(3, A) OP(4, A) OP(5, A) OP(6, A) OP(7, A) \
  OP(8, A) OP(9, A) OP(10, A) OP(11, A) OP(12, A) OP(13, A) OP(14, A) OP(15, A)

// One block per (b, h, group of QB=4 queries). Score GEMM is block-cooperative
// through a CHUNK-key LDS window; wave w keeps query w's full key set in 16
// NAMED uint4 registers, then radix-selects top-128 with exact lowest-index
// tie ranking, softmax, V gather.
// NOTE: __launch_bounds__(256) with NO min-waves clause. r4-r6 lesson: a
// min-waves=3 clause caps VGPR at ~170 and the allocator cascade-spills the
// 64 key registers -> 9.6GB scratch traffic/dispatch, 100% of runtime.
// Occupancy is LDS-capped anyway, so the cap bought nothing.
template <int N>
__global__ __launch_bounds__(256) void attn_kernel(
    const float* __restrict__ Q, const float* __restrict__ Kt, const float* __restrict__ V,
    float* __restrict__ O) {
  constexpr int CHUNK = (N > 2048) ? 2048 : N;   // LDS staging window
  constexpr int NCH = N / CHUNK;                 // 1 or 2
  constexpr int NQ4 = CHUNK / 256;               // uint4 regs per lane per chunk
  constexpr int NV4 = N / 256;                   // total uint4 regs per lane (<=16)
  extern __shared__ unsigned sb[];               // QB * CHUNK keys
  __shared__ float qv[QB][HD];
  __shared__ unsigned hist[4][256];
  __shared__ int idxb[4][KSEL];
  __shared__ float wb[4][KSEL];

  const int tid = threadIdx.x;
  const int nq = N / QB;
  const int qg = blockIdx.x % nq;
  const int h = (blockIdx.x / nq) & 3;
  const int b = blockIdx.x / (4 * nq);
  const int q0 = qg * QB;
  const float scale = 0.14433756729740643f;  // 1/sqrt(48)

  if (tid < QB * HD) {
    int q = tid / HD, d = tid - q * HD;
    qv[q][d] = Q[((size_t)(b * N + q0 + q)) * TD + h * HD + d];
  }
  __syncthreads();

  const int w = tid >> 6, lane = tid & 63;
  const unsigned long long lanelt = (1ull << lane) - 1ull;
  const float* kt = Kt + ((size_t)(b * 4 + h) * HD) * N;

  uint4 k0 = make_uint4(0,0,0,0), k1 = k0, k2 = k0, k3 = k0, k4 = k0, k5 = k0,
        k6 = k0, k7 = k0, k8 = k0, k9 = k0, k10 = k0, k11 = k0, k12 = k0,
        k13 = k0, k14 = k0, k15 = k0;

#define LOAD_KEY(i, CH) \
  if constexpr ((i) >= (CH) * NQ4 && (i) < ((CH) + 1) * NQ4 && (i) < NV4) { \
    k##i = *reinterpret_cast<const uint4*>(&sq[((i) - (CH) * NQ4) * 256 + lane * 4]); }

#define GEMM_CHUNK(CH) { \
    const int jbase = (CH) * CHUNK; \
    for (int j0 = tid * 4; j0 < CHUNK; j0 += 1024) { \
      float4 acc[QB]; \
      _Pragma("unroll") for (int q = 0; q < QB; ++q) acc[q] = make_float4(0.f, 0.f, 0.f, 0.f); \
      _Pragma("unroll") for (int d4 = 0; d4 < HD; d4 += 4) { \
        float4 kk0 = *reinterpret_cast<const float4*>(kt + (size_t)(d4 + 0) * N + jbase + j0); \
        float4 kk1 = *reinterpret_cast<const float4*>(kt + (size_t)(d4 + 1) * N + jbase + j0); \
        float4 kk2 = *reinterpret_cast<const float4*>(kt + (size_t)(d4 + 2) * N + jbase + j0); \
        float4 kk3 = *reinterpret_cast<const float4*>(kt + (size_t)(d4 + 3) * N + jbase + j0); \
        _Pragma("unroll") for (int q = 0; q < QB; ++q) { \
          float4 qq = *reinterpret_cast<const float4*>(&qv[q][d4]); \
          acc[q].x = fmaf(qq.x, kk0.x, acc[q].x); acc[q].x = fmaf(qq.y, kk1.x, acc[q].x); \
          acc[q].x = fmaf(qq.z, kk2.x, acc[q].x); acc[q].x = fmaf(qq.w, kk3.x, acc[q].x); \
          acc[q].y = fmaf(qq.x, kk0.y, acc[q].y); acc[q].y = fmaf(qq.y, kk1.y, acc[q].y); \
          acc[q].y = fmaf(qq.z, kk2.y, acc[q].y); acc[q].y = fmaf(qq.w, kk3.y, acc[q].y); \
          acc[q].z = fmaf(qq.x, kk0.z, acc[q].z); acc[q].z = fmaf(qq.y, kk1.z, acc[q].z); \
          acc[q].z = fmaf(qq.z, kk2.z, acc[q].z); acc[q].z = fmaf(qq.w, kk3.z, acc[q].z); \
          acc[q].w = fmaf(qq.x, kk0.w, acc[q].w); acc[q].w = fmaf(qq.y, kk1.w, acc[q].w); \
          acc[q].w = fmaf(qq.z, kk2.w, acc[q].w); acc[q].w = fmaf(qq.w, kk3.w, acc[q].w); \
        } \
      } \
      _Pragma("unroll") for (int q = 0; q < QB; ++q) { \
        uint4 kk; \
        kk.x = f2o(acc[q].x * scale); kk.y = f2o(acc[q].y * scale); \
        kk.z = f2o(acc[q].z * scale); kk.w = f2o(acc[q].w * scale); \
        *reinterpret_cast<uint4*>(&sb[q * CHUNK + j0]) = kk; \
      } \
    } \
    __syncthreads(); \
    { const unsigned* sq = sb + w * CHUNK; KAPPLY(LOAD_KEY, CH) } \
    __syncthreads(); }

  GEMM_CHUNK(0)
  if constexpr (NCH > 1) { GEMM_CHUNK(1) }
  // reg i holds global keys j = (i/NQ4)*CHUNK + (i%NQ4)*256 + lane*4 + c.

  // ---- global max (f2o order-preserving) ----
  unsigned mk = 0u;
#define MAXK(i, A) if constexpr ((i) < NV4) { \
    unsigned a_ = k##i.x > k##i.y ? k##i.x : k##i.y; \
    unsigned b_ = k##i.z > k##i.w ? k##i.z : k##i.w; \
    a_ = a_ > b_ ? a_ : b_; mk = a_ > mk ? a_ : mk; }
  KAPPLY(MAXK, 0)
  for (int off = 32; off > 0; off >>= 1) {
    unsigned o = (unsigned)__shfl_xor((int)mk, off, 64);
    mk = o > mk ? o : mk;
  }
  const float mx = o2f(mk);

  // ---- radix select: kth-largest key (k=128) ----
  unsigned* hw = hist[w];
  unsigned kth = 0u, mask = 0u;
  int rem = KSEL;
#define HISTK(i, A) if constexpr ((i) < NV4) { \
    if ((k##i.x & mask) == kth) atomicAdd(&hw[(k##i.x >> shift) & 255u], 1u); \
    if ((k##i.y & mask) == kth) atomicAdd(&hw[(k##i.y >> shift) & 255u], 1u); \
    if ((k##i.z & mask) == kth) atomicAdd(&hw[(k##i.z >> shift) & 255u], 1u); \
    if ((k##i.w & mask) == kth) atomicAdd(&hw[(k##i.w >> shift) & 255u], 1u); }
  for (int shift = 24; shift >= 0; shift -= 8) {
#pragma unroll
    for (int i = 0; i < 4; ++i) hw[lane + i * 64] = 0u;
    KAPPLY(HISTK, 0)
    // wave suffix-scan over 256 bins, 4 bins/lane descending
    int v[4], loc = 0;
#pragma unroll
    for (int i = 0; i < 4; ++i) { v[i] = (int)hw[255 - (lane * 4 + i)]; loc += v[i]; }
    int incl = loc;
#pragma unroll
    for (int off = 1; off < 64; off <<= 1) {
      int t = __shfl_up(incl, off, 64);
      if (lane >= off) incl += t;
    }
    int c = incl - loc;  // count in bins strictly above this lane's bins
    int selidx = -1, selexcl = 0;
#pragma unroll
    for (int i = 0; i < 4; ++i) {
      if (selidx < 0 && rem > c && rem <= c + v[i]) {
        selidx = 255 - (lane * 4 + i); selexcl = c;
      }
      c += v[i];
    }
    unsigned long long vote = __ballot(selidx >= 0);
    int src = __ffsll((long long)vote) - 1;
    selidx = __shfl(selidx, src, 64);
    selexcl = __shfl(selexcl, src, 64);
    rem -= selexcl;
    kth |= ((unsigned)selidx << shift);
    mask |= (0xFFu << shift);
  }
  const int need_eq = rem;   // boundary slots among ==kth, lowest index first

  // ---- compact: exact j-ascending tie ranking via ballot ranks ----
  int selbase = 0, eqbase = 0;
  float lz = 0.f;
#define COMPACT_K(i, A) if constexpr ((i) < NV4) { \
    constexpr int regj = ((i) / NQ4) * CHUNK + ((i) % NQ4) * 256; \
    const unsigned u0 = k##i.x, u1 = k##i.y, u2 = k##i.z, u3 = k##i.w; \
    const bool e0 = (u0 == kth), e1 = (u1 == kth), e2 = (u2 == kth), e3 = (u3 == kth); \
    const unsigned long long b0 = __ballot(e0), b1 = __ballot(e1), b2 = __ballot(e2), b3 = __ballot(e3); \
    const int eqlt = __popcll(b0 & lanelt) + __popcll(b1 & lanelt) + __popcll(b2 & lanelt) + __popcll(b3 & lanelt); \
    int eo = 0; \
    const bool s0 = (u0 > kth) || (e0 && (eqbase + eqlt + eo) < need_eq); eo += e0 ? 1 : 0; \
    const bool s1 = (u1 > kth) || (e1 && (eqbase + eqlt + eo) < need_eq); eo += e1 ? 1 : 0; \
    const bool s2 = (u2 > kth) || (e2 && (eqbase + eqlt + eo) < need_eq); eo += e2 ? 1 : 0; \
    const bool s3 = (u3 > kth) || (e3 && (eqbase + eqlt + eo) < need_eq); eo += e3 ? 1 : 0; \
    const unsigned long long c0 = __ballot(s0), c1 = __ballot(s1), c2 = __ballot(s2), c3 = __ballot(s3); \
    const int sellt = __popcll(c0 & lanelt) + __popcll(c1 & lanelt) + __popcll(c2 & lanelt) + __popcll(c3 & lanelt); \
    int so = 0; \
    if (s0) { int pos = selbase + sellt + so; float e = expf(o2f(u0) - mx); idxb[w][pos] = regj + lane * 4 + 0; wb[w][pos] = e; lz += e; } so += s0 ? 1 : 0; \
    if (s1) { int pos = selbase + sellt + so; float e = expf(o2f(u1) - mx); idxb[w][pos] = regj + lane * 4 + 1; wb[w][pos] = e; lz += e; } so += s1 ? 1 : 0; \
    if (s2) { int pos = selbase + sellt + so; float e = expf(o2f(u2) - mx); idxb[w][pos] = regj + lane * 4 + 2; wb[w][pos] = e; lz += e; } so += s2 ? 1 : 0; \
    if (s3) { int pos = selbase + sellt + so; float e = expf(o2f(u3) - mx); idxb[w][pos] = regj + lane * 4 + 3; wb[w][pos] = e; lz += e; } so += s3 ? 1 : 0; \
    eqbase += __popcll(b0) + __popcll(b1) + __popcll(b2) + __popcll(b3); \
    selbase += __popcll(c0) + __popcll(c1) + __popcll(c2) + __popcll(c3); }
  KAPPLY(COMPACT_K, 0)
  for (int off = 32; off > 0; off >>= 1) lz += __shfl_xor(lz, off, 64);
  const float rz = 1.f / lz;

  // ---- gather V (per wave, lane = dim) ----
  if (lane < HD) {
    float acc = 0.f;
#pragma unroll 4
    for (int p = 0; p < KSEL; ++p) {
      acc = fmaf(wb[w][p], V[((size_t)(b * N + idxb[w][p])) * TD + h * HD + lane], acc);
    }
    O[((size_t)(b * N + q0 + w)) * TD + h * HD + lane] = acc * rz;
  }
}

// out[b, t, n0+nl] = O[b, n0+nl, :] . ow[:, t] + ob[t]; 64-token LDS tile.
#define TOK 64
__global__ __launch_bounds__(256) void oproj_kernel(
    const float* __restrict__ O, const float* __restrict__ ow,
    const float* __restrict__ ob, float* __restrict__ out, int N) {
  __shared__ float otile[TOK][TD + 1];
  const int tid = threadIdx.x;
  const int nt = N / TOK;
  const int b = blockIdx.x / nt;
  const int n0 = (blockIdx.x % nt) * TOK;
  const float* obase = O + ((size_t)(b * N + n0)) * TD;
  for (int idx = tid * 4; idx < TOK * TD; idx += 1024) {
    float4 v = *reinterpret_cast<const float4*>(obase + idx);
    int r = idx / TD, c = idx - r * TD;
    otile[r][c] = v.x; otile[r][c + 1] = v.y; otile[r][c + 2] = v.z; otile[r][c + 3] = v.w;
  }
  __syncthreads();
  const int nl = tid >> 2;            // 0..63 token
  const int ts = (tid & 3) * 48;      // output-channel group
  float acc[48];
#pragma unroll
  for (int i = 0; i < 48; ++i) acc[i] = 0.f;
  for (int c = 0; c < TD; ++c) {
    float oval = otile[nl][c];
    const float* wr = ow + c * TD + ts;
#pragma unroll
    for (int i = 0; i < 48; ++i) acc[i] = fmaf(oval, wr[i], acc[i]);
  }
#pragma unroll
  for (int i = 0; i < 48; ++i) {
    int t = ts + i;
    out[((size_t)(b * TD + t)) * N + n0 + nl] = acc[i] + ob[t];
  }
}

extern "C" void kernel_launch(void* const* d_in, const int* in_sizes, int n_in,
                              void* d_out, int out_size, void* d_ws, size_t ws_size,
                              hipStream_t stream) {
  const int B = 2;
  const int Cs[3] = {64, 128, 192};
  const int Hs[3] = {64, 32, 16};
  const size_t out_off[3] = {0,
                             (size_t)2 * TD * 64 * 64,
                             (size_t)2 * TD * 64 * 64 + (size_t)2 * TD * 32 * 32};

  float* ws = (float*)d_ws;
  float* pe = ws;                                 // 4096*192
  float* Q = pe + (size_t)4096 * TD;              // 2*4096*192
  float* Kt = Q + (size_t)B * 4096 * TD;
  float* V = Kt + (size_t)B * 4096 * TD;
  float* Obuf = V + (size_t)B * 4096 * TD;

  for (int lvl = 0; lvl < 3; ++lvl) {
    int C = Cs[lvl], H = Hs[lvl], W = H, N = H * W;
    const float* feat1 = (const float*)d_in[lvl * 2 + 0];
    const float* feat2 = (const float*)d_in[lvl * 2 + 1];
    const float* qw = (const float*)d_in[6 + lvl * 8 + 0];
    const float* qb = (const float*)d_in[6 + lvl * 8 + 1];
    const float* kw = (const float*)d_in[6 + lvl * 8 + 2];
    const float* kb = (const float*)d_in[6 + lvl * 8 + 3];
    const float* vw = (const float*)d_in[6 + lvl * 8 + 4];
    const float* vb = (const float*)d_in[6 + lvl * 8 + 5];
    const float* ow = (const float*)d_in[6 + lvl * 8 + 6];
    const float* ob = (const float*)d_in[6 + lvl * 8 + 7];

    pe_kernel<<<N, TD, 0, stream>>>(pe, W);
    qkv_kernel<<<B * N, TD, 0, stream>>>(feat1, feat2, qw, qb, kw, kb, vw, vb, pe, Q, Kt, V, C, N);
    int chunk = N > 2048 ? 2048 : N;
    size_t shm = (size_t)QB * chunk * sizeof(unsigned);
    int nblk = B * 4 * (N / QB);
    if (N == 4096)      attn_kernel<4096><<<nblk, 256, shm, stream>>>(Q, Kt, V, Obuf);
    else if (N == 1024) attn_kernel<1024><<<nblk, 256, shm, stream>>>(Q, Kt, V, Obuf);
    else                attn_kernel<256><<<nblk, 256, shm, stream>>>(Q, Kt, V, Obuf);
    oproj_kernel<<<B * (N / TOK), 256, 0, stream>>>(Obuf, ow, ob, (float*)d_out + out_off[lvl], N);
  }
}

// Round 10
// 2062.428 us; speedup vs baseline: 2.1278x; 1.4010x over previous
//
#include <hip/hip_runtime.h>
#include <math.h>

#define TD 192
#define HD 48
#define KSEL 128
#define QB 4

// Map float to orderable unsigned: a > b (float) <=> f2o(a) > f2o(b)
__device__ __forceinline__ unsigned f2o(float f) {
  unsigned u = __float_as_uint(f);
  return (u & 0x80000000u) ? ~u : (u | 0x80000000u);
}
__device__ __forceinline__ float o2f(unsigned u) {
  unsigned v = (u & 0x80000000u) ? (u & 0x7fffffffu) : ~u;
  return __uint_as_float(v);
}

// 2D sinusoidal positional encoding, matches reference _pos_enc.
__global__ void pe_kernel(float* __restrict__ pe, int W) {
  int n = blockIdx.x;
  int t = threadIdx.x;                      // 0..191
  const float c = -0.09594104554885301f;    // -ln(10000)/96
  float val;
  if (t < 96) {
    float dv = expf((float)t * c);
    val = sinf((float)(n % W) * dv);
  } else {
    float dv = expf((float)(t - 96) * c);
    val = cosf((float)(n / W) * dv);
  }
  pe[n * TD + t] = val;
}

// Q = f1@qw+qb+pe (row-major), Kt = (f2@kw+kb+pe)^T -> [b][h][d][N], V row-major
__global__ void qkv_kernel(const float* __restrict__ feat1, const float* __restrict__ feat2,
                           const float* __restrict__ qw, const float* __restrict__ qb,
                           const float* __restrict__ kw, const float* __restrict__ kb,
                           const float* __restrict__ vw, const float* __restrict__ vb,
                           const float* __restrict__ pe,
                           float* __restrict__ Q, float* __restrict__ Kt, float* __restrict__ V,
                           int C, int N) {
  int t = threadIdx.x;            // 0..191
  int bn = blockIdx.x;            // b*N + n
  int b = bn / N, n = bn - b * N;
  const float* f1 = feat1 + (size_t)b * C * N + n;
  const float* f2 = feat2 + (size_t)b * C * N + n;
  float q = 0.f, k = 0.f, v = 0.f;
  for (int c = 0; c < C; ++c) {
    float a1 = f1[(size_t)c * N];
    float a2 = f2[(size_t)c * N];
    q = fmaf(a1, qw[c * TD + t], q);
    k = fmaf(a2, kw[c * TD + t], k);
    v = fmaf(a2, vw[c * TD + t], v);
  }
  float p = pe[n * TD + t];
  size_t o = (size_t)bn * TD + t;
  Q[o] = q + qb[t] + p;
  V[o] = v + vb[t];
  int h = t / HD, d = t - h * HD;
  Kt[(((size_t)b * 4 + h) * HD + d) * N + n] = k + kb[t] + p;
}

// ---------------- Stage A (one (b,h) pair per launch) ----------------
// Block = (4 queries, key-range of RK). Cooperative score GEMM -> LDS, wave w
// owns query w with RK/64 keys/lane in registers, radix-select per-range
// top-128 with exact lowest-index ties, write (key u32, idx u16) candidates.
// Split correctness: a global-top-128 element has <=127 global predecessors
// under (key desc, idx asc) => <=127 in-range predecessors => in range top-128.
template <int N, int RK>
__global__ __launch_bounds__(256) void attnA_kernel(
    const float* __restrict__ Q, const float* __restrict__ Kt,
    unsigned* __restrict__ ckey, unsigned short* __restrict__ cidx,
    int b, int h) {
  constexpr int R = N / RK;
  constexpr int NV4 = RK / 256;           // uint4 regs per lane (<=4)
  __shared__ unsigned sb[QB * RK];        // 16 KB at RK=1024
  __shared__ float qv[QB][HD];
  __shared__ unsigned hist[4][256];

  const int tid = threadIdx.x;
  const int r = blockIdx.x % R;
  const int qg = blockIdx.x / R;
  const int q0 = qg * QB;
  const float scale = 0.14433756729740643f;  // 1/sqrt(48)

  if (tid < QB * HD) {
    int q = tid / HD, d = tid - q * HD;
    qv[q][d] = Q[((size_t)(b * N + q0 + q)) * TD + h * HD + d];
  }
  __syncthreads();

  const int w = tid >> 6, lane = tid & 63;
  const unsigned long long lanelt = (1ull << lane) - 1ull;
  const float* kt = Kt + ((size_t)(b * 4 + h) * HD) * N + r * RK;

  // ---- score GEMM for this range (4 keys x 4 queries per thread iter) ----
  for (int j0 = tid * 4; j0 < RK; j0 += 1024) {
    float4 acc[QB];
#pragma unroll
    for (int q = 0; q < QB; ++q) acc[q] = make_float4(0.f, 0.f, 0.f, 0.f);
#pragma unroll
    for (int d4 = 0; d4 < HD; d4 += 4) {
      float4 k0 = *reinterpret_cast<const float4*>(kt + (size_t)(d4 + 0) * N + j0);
      float4 k1 = *reinterpret_cast<const float4*>(kt + (size_t)(d4 + 1) * N + j0);
      float4 k2 = *reinterpret_cast<const float4*>(kt + (size_t)(d4 + 2) * N + j0);
      float4 k3 = *reinterpret_cast<const float4*>(kt + (size_t)(d4 + 3) * N + j0);
#pragma unroll
      for (int q = 0; q < QB; ++q) {
        float4 qq = *reinterpret_cast<const float4*>(&qv[q][d4]);
        acc[q].x = fmaf(qq.x, k0.x, acc[q].x); acc[q].x = fmaf(qq.y, k1.x, acc[q].x);
        acc[q].x = fmaf(qq.z, k2.x, acc[q].x); acc[q].x = fmaf(qq.w, k3.x, acc[q].x);
        acc[q].y = fmaf(qq.x, k0.y, acc[q].y); acc[q].y = fmaf(qq.y, k1.y, acc[q].y);
        acc[q].y = fmaf(qq.z, k2.y, acc[q].y); acc[q].y = fmaf(qq.w, k3.y, acc[q].y);
        acc[q].z = fmaf(qq.x, k0.z, acc[q].z); acc[q].z = fmaf(qq.y, k1.z, acc[q].z);
        acc[q].z = fmaf(qq.z, k2.z, acc[q].z); acc[q].z = fmaf(qq.w, k3.z, acc[q].z);
        acc[q].w = fmaf(qq.x, k0.w, acc[q].w); acc[q].w = fmaf(qq.y, k1.w, acc[q].w);
        acc[q].w = fmaf(qq.z, k2.w, acc[q].w); acc[q].w = fmaf(qq.w, k3.w, acc[q].w);
      }
    }
#pragma unroll
    for (int q = 0; q < QB; ++q) {
      uint4 kk;
      kk.x = f2o(acc[q].x * scale); kk.y = f2o(acc[q].y * scale);
      kk.z = f2o(acc[q].z * scale); kk.w = f2o(acc[q].w * scale);
      *reinterpret_cast<uint4*>(&sb[q * RK + j0]) = kk;
    }
  }
  __syncthreads();

  // ---- per-wave: keys -> registers (RK/64 per lane) ----
  uint4 kr[NV4];
#pragma unroll
  for (int i = 0; i < NV4; ++i)
    kr[i] = *reinterpret_cast<const uint4*>(&sb[w * RK + i * 256 + lane * 4]);

  // ---- radix select: 128th largest within range ----
  unsigned* hw = hist[w];
  unsigned kth = 0u, mask = 0u;
  int rem = KSEL;
#pragma unroll
  for (int shift = 24; shift >= 0; shift -= 8) {
#pragma unroll
    for (int i = 0; i < 4; ++i) hw[lane + i * 64] = 0u;
#pragma unroll
    for (int i = 0; i < NV4; ++i) {
      if ((kr[i].x & mask) == kth) atomicAdd(&hw[(kr[i].x >> shift) & 255u], 1u);
      if ((kr[i].y & mask) == kth) atomicAdd(&hw[(kr[i].y >> shift) & 255u], 1u);
      if ((kr[i].z & mask) == kth) atomicAdd(&hw[(kr[i].z >> shift) & 255u], 1u);
      if ((kr[i].w & mask) == kth) atomicAdd(&hw[(kr[i].w >> shift) & 255u], 1u);
    }
    int v[4], loc = 0;
#pragma unroll
    for (int i = 0; i < 4; ++i) { v[i] = (int)hw[255 - (lane * 4 + i)]; loc += v[i]; }
    int incl = loc;
#pragma unroll
    for (int off = 1; off < 64; off <<= 1) {
      int t = __shfl_up(incl, off, 64);
      if (lane >= off) incl += t;
    }
    int c = incl - loc;
    int selidx = -1, selexcl = 0;
#pragma unroll
    for (int i = 0; i < 4; ++i) {
      if (selidx < 0 && rem > c && rem <= c + v[i]) {
        selidx = 255 - (lane * 4 + i); selexcl = c;
      }
      c += v[i];
    }
    unsigned long long vote = __ballot(selidx >= 0);
    int src = __ffsll((long long)vote) - 1;
    selidx = __shfl(selidx, src, 64);
    selexcl = __shfl(selexcl, src, 64);
    rem -= selexcl;
    kth |= ((unsigned)selidx << shift);
    mask |= (0xFFu << shift);
  }
  const int need_eq = rem;

  // ---- compact: exact j-ascending tie ranking, write candidates ----
  unsigned* ok = ckey + ((size_t)(q0 + w) * R + r) * KSEL;
  unsigned short* oi = cidx + ((size_t)(q0 + w) * R + r) * KSEL;
  int selbase = 0, eqbase = 0;
#pragma unroll
  for (int i = 0; i < NV4; ++i) {
    const int jb = r * RK + i * 256 + lane * 4;   // global key index of .x
    const unsigned u0 = kr[i].x, u1 = kr[i].y, u2 = kr[i].z, u3 = kr[i].w;
    const bool e0 = (u0 == kth), e1 = (u1 == kth), e2 = (u2 == kth), e3 = (u3 == kth);
    const unsigned long long b0 = __ballot(e0), b1 = __ballot(e1), b2 = __ballot(e2), b3 = __ballot(e3);
    const int eqlt = __popcll(b0 & lanelt) + __popcll(b1 & lanelt) + __popcll(b2 & lanelt) + __popcll(b3 & lanelt);
    int eo = 0;
    const bool s0 = (u0 > kth) || (e0 && (eqbase + eqlt + eo) < need_eq); eo += e0 ? 1 : 0;
    const bool s1 = (u1 > kth) || (e1 && (eqbase + eqlt + eo) < need_eq); eo += e1 ? 1 : 0;
    const bool s2 = (u2 > kth) || (e2 && (eqbase + eqlt + eo) < need_eq); eo += e2 ? 1 : 0;
    const bool s3 = (u3 > kth) || (e3 && (eqbase + eqlt + eo) < need_eq); eo += e3 ? 1 : 0;
    const unsigned long long c0 = __ballot(s0), c1 = __ballot(s1), c2 = __ballot(s2), c3 = __ballot(s3);
    const int sellt = __popcll(c0 & lanelt) + __popcll(c1 & lanelt) + __popcll(c2 & lanelt) + __popcll(c3 & lanelt);
    int so = 0;
    if (s0) { int p = selbase + sellt + so; ok[p] = u0; oi[p] = (unsigned short)(jb + 0); } so += s0 ? 1 : 0;
    if (s1) { int p = selbase + sellt + so; ok[p] = u1; oi[p] = (unsigned short)(jb + 1); } so += s1 ? 1 : 0;
    if (s2) { int p = selbase + sellt + so; ok[p] = u2; oi[p] = (unsigned short)(jb + 2); } so += s2 ? 1 : 0;
    if (s3) { int p = selbase + sellt + so; ok[p] = u3; oi[p] = (unsigned short)(jb + 3); } so += s3 ? 1 : 0;
    eqbase += __popcll(b0) + __popcll(b1) + __popcll(b2) + __popcll(b3);
    selbase += __popcll(c0) + __popcll(c1) + __popcll(c2) + __popcll(c3);
  }
}

// ---------------- Stage B (one (b,h) pair per launch) ----------------
// Wave per query: load CN candidates (ascending global index by construction,
// so ballot order == tie order), radix-select global top-128, softmax, gather V.
template <int CN>
__global__ __launch_bounds__(256) void attnB_kernel(
    const unsigned* __restrict__ ckey, const unsigned short* __restrict__ cidx,
    const float* __restrict__ V, float* __restrict__ O, int N, int b, int h) {
  constexpr int CL = CN / 64;             // candidates per lane (8 or 2)
  __shared__ unsigned hist[4][256];
  __shared__ int idxb[4][KSEL];
  __shared__ float wb[4][KSEL];

  const int tid = threadIdx.x, w = tid >> 6, lane = tid & 63;
  const unsigned long long lanelt = (1ull << lane) - 1ull;
  const int qi = blockIdx.x * 4 + w;      // query id within this (b,h)

  unsigned ck[CL], ci[CL];
#pragma unroll
  for (int i = 0; i < CL; ++i) {
    ck[i] = ckey[(size_t)qi * CN + i * 64 + lane];
    ci[i] = cidx[(size_t)qi * CN + i * 64 + lane];
  }

  // global max (top-1 is always a candidate)
  unsigned mk = 0u;
#pragma unroll
  for (int i = 0; i < CL; ++i) mk = ck[i] > mk ? ck[i] : mk;
  for (int off = 32; off > 0; off >>= 1) {
    unsigned o = (unsigned)__shfl_xor((int)mk, off, 64);
    mk = o > mk ? o : mk;
  }
  const float mx = o2f(mk);

  // radix select 128th largest among CN candidates
  unsigned* hw = hist[w];
  unsigned kth = 0u, mask = 0u;
  int rem = KSEL;
#pragma unroll
  for (int shift = 24; shift >= 0; shift -= 8) {
#pragma unroll
    for (int i = 0; i < 4; ++i) hw[lane + i * 64] = 0u;
#pragma unroll
    for (int i = 0; i < CL; ++i)
      if ((ck[i] & mask) == kth) atomicAdd(&hw[(ck[i] >> shift) & 255u], 1u);
    int v[4], loc = 0;
#pragma unroll
    for (int i = 0; i < 4; ++i) { v[i] = (int)hw[255 - (lane * 4 + i)]; loc += v[i]; }
    int incl = loc;
#pragma unroll
    for (int off = 1; off < 64; off <<= 1) {
      int t = __shfl_up(incl, off, 64);
      if (lane >= off) incl += t;
    }
    int c = incl - loc;
    int selidx = -1, selexcl = 0;
#pragma unroll
    for (int i = 0; i < 4; ++i) {
      if (selidx < 0 && rem > c && rem <= c + v[i]) {
        selidx = 255 - (lane * 4 + i); selexcl = c;
      }
      c += v[i];
    }
    unsigned long long vote = __ballot(selidx >= 0);
    int src = __ffsll((long long)vote) - 1;
    selidx = __shfl(selidx, src, 64);
    selexcl = __shfl(selexcl, src, 64);
    rem -= selexcl;
    kth |= ((unsigned)selidx << shift);
    mask |= (0xFFu << shift);
  }
  const int need_eq = rem;

  // compact (candidate-array order == ascending global index == tie order)
  int selbase = 0, eqbase = 0;
  float lz = 0.f;
#pragma unroll
  for (int i = 0; i < CL; ++i) {
    const unsigned u = ck[i];
    const bool eq = (u == kth);
    const unsigned long long beq = __ballot(eq);
    const int eqrank = eqbase + __popcll(beq & lanelt);
    const bool sel = (u > kth) || (eq && eqrank < need_eq);
    const unsigned long long bsel = __ballot(sel);
    const int pos = selbase + __popcll(bsel & lanelt);
    if (sel) {
      float e = expf(o2f(u) - mx);
      idxb[w][pos] = (int)ci[i];
      wb[w][pos] = e;
      lz += e;
    }
    eqbase += __popcll(beq);
    selbase += __popcll(bsel);
  }
  for (int off = 32; off > 0; off >>= 1) lz += __shfl_xor(lz, off, 64);
  const float rz = 1.f / lz;

  // gather V (lane = dim)
  if (lane < HD) {
    float acc = 0.f;
#pragma unroll 4
    for (int p = 0; p < KSEL; ++p) {
      acc = fmaf(wb[w][p], V[((size_t)(b * N + idxb[w][p])) * TD + h * HD + lane], acc);
    }
    O[((size_t)(b * N + qi)) * TD + h * HD + lane] = acc * rz;
  }
}

// out[b, t, n0+nl] = O[b, n0+nl, :] . ow[:, t] + ob[t]; 64-token LDS tile.
#define TOK 64
__global__ __launch_bounds__(256) void oproj_kernel(
    const float* __restrict__ O, const float* __restrict__ ow,
    const float* __restrict__ ob, float* __restrict__ out, int N) {
  __shared__ float otile[TOK][TD + 1];
  const int tid = threadIdx.x;
  const int nt = N / TOK;
  const int b = blockIdx.x / nt;
  const int n0 = (blockIdx.x % nt) * TOK;
  const float* obase = O + ((size_t)(b * N + n0)) * TD;
  for (int idx = tid * 4; idx < TOK * TD; idx += 1024) {
    float4 v = *reinterpret_cast<const float4*>(obase + idx);
    int r = idx / TD, c = idx - r * TD;
    otile[r][c] = v.x; otile[r][c + 1] = v.y; otile[r][c + 2] = v.z; otile[r][c + 3] = v.w;
  }
  __syncthreads();
  const int nl = tid >> 2;            // 0..63 token
  const int ts = (tid & 3) * 48;      // output-channel group
  float acc[48];
#pragma unroll
  for (int i = 0; i < 48; ++i) acc[i] = 0.f;
  for (int c = 0; c < TD; ++c) {
    float oval = otile[nl][c];
    const float* wr = ow + c * TD + ts;
#pragma unroll
    for (int i = 0; i < 48; ++i) acc[i] = fmaf(oval, wr[i], acc[i]);
  }
#pragma unroll
  for (int i = 0; i < 48; ++i) {
    int t = ts + i;
    out[((size_t)(b * TD + t)) * N + n0 + nl] = acc[i] + ob[t];
  }
}

extern "C" void kernel_launch(void* const* d_in, const int* in_sizes, int n_in,
                              void* d_out, int out_size, void* d_ws, size_t ws_size,
                              hipStream_t stream) {
  const int B = 2;
  const int Cs[3] = {64, 128, 192};
  const int Hs[3] = {64, 32, 16};
  const size_t out_off[3] = {0,
                             (size_t)2 * TD * 64 * 64,
                             (size_t)2 * TD * 64 * 64 + (size_t)2 * TD * 32 * 32};

  float* ws = (float*)d_ws;
  float* pe = ws;                                 // 4096*192 = 3.1 MB
  float* Q = pe + (size_t)4096 * TD;              // each 6.3 MB
  float* Kt = Q + (size_t)B * 4096 * TD;
  float* V = Kt + (size_t)B * 4096 * TD;
  float* Obuf = V + (size_t)B * 4096 * TD;
  // candidate buffers sized for ONE (b,h): 4096 queries x 512 cand max
  unsigned* ckey = (unsigned*)(Obuf + (size_t)B * 4096 * TD);           // 8.4 MB
  unsigned short* cidx = (unsigned short*)(ckey + (size_t)4096 * 512);  // 4.2 MB
  // total ws usage ~41 MB

  for (int lvl = 0; lvl < 3; ++lvl) {
    int C = Cs[lvl], H = Hs[lvl], W = H, N = H * W;
    const float* feat1 = (const float*)d_in[lvl * 2 + 0];
    const float* feat2 = (const float*)d_in[lvl * 2 + 1];
    const float* qw = (const float*)d_in[6 + lvl * 8 + 0];
    const float* qb = (const float*)d_in[6 + lvl * 8 + 1];
    const float* kw = (const float*)d_in[6 + lvl * 8 + 2];
    const float* kb = (const float*)d_in[6 + lvl * 8 + 3];
    const float* vw = (const float*)d_in[6 + lvl * 8 + 4];
    const float* vb = (const float*)d_in[6 + lvl * 8 + 5];
    const float* ow = (const float*)d_in[6 + lvl * 8 + 6];
    const float* ob = (const float*)d_in[6 + lvl * 8 + 7];

    pe_kernel<<<N, TD, 0, stream>>>(pe, W);
    qkv_kernel<<<B * N, TD, 0, stream>>>(feat1, feat2, qw, qb, kw, kb, vw, vb, pe, Q, Kt, V, C, N);

    for (int bh = 0; bh < 8; ++bh) {
      int b = bh >> 2, h = bh & 3;
      if (N == 4096) {
        attnA_kernel<4096, 1024><<<(4096 / QB) * 4, 256, 0, stream>>>(Q, Kt, ckey, cidx, b, h);
        attnB_kernel<512><<<4096 / 4, 256, 0, stream>>>(ckey, cidx, V, Obuf, 4096, b, h);
      } else if (N == 1024) {
        attnA_kernel<1024, 1024><<<1024 / QB, 256, 0, stream>>>(Q, Kt, ckey, cidx, b, h);
        attnB_kernel<128><<<1024 / 4, 256, 0, stream>>>(ckey, cidx, V, Obuf, 1024, b, h);
      } else {
        attnA_kernel<256, 256><<<256 / QB, 256, 0, stream>>>(Q, Kt, ckey, cidx, b, h);
        attnB_kernel<128><<<256 / 4, 256, 0, stream>>>(ckey, cidx, V, Obuf, 256, b, h);
      }
    }
    oproj_kernel<<<B * (N / TOK), 256, 0, stream>>>(Obuf, ow, ob, (float*)d_out + out_off[lvl], N);
  }
}

// Round 11
// 1385.340 us; speedup vs baseline: 3.1678x; 1.4888x over previous
//
#include <hip/hip_runtime.h>
#include <math.h>

#define TD 192
#define HD 48
#define KSEL 128
#define QB 4

// Map float to orderable unsigned: a > b (float) <=> f2o(a) > f2o(b)
__device__ __forceinline__ unsigned f2o(float f) {
  unsigned u = __float_as_uint(f);
  return (u & 0x80000000u) ? ~u : (u | 0x80000000u);
}
__device__ __forceinline__ float o2f(unsigned u) {
  unsigned v = (u & 0x80000000u) ? (u & 0x7fffffffu) : ~u;
  return __uint_as_float(v);
}

// 2D sinusoidal positional encoding, matches reference _pos_enc.
__global__ void pe_kernel(float* __restrict__ pe, int W) {
  int n = blockIdx.x;
  int t = threadIdx.x;                      // 0..191
  const float c = -0.09594104554885301f;    // -ln(10000)/96
  float val;
  if (t < 96) {
    float dv = expf((float)t * c);
    val = sinf((float)(n % W) * dv);
  } else {
    float dv = expf((float)(t - 96) * c);
    val = cosf((float)(n / W) * dv);
  }
  pe[n * TD + t] = val;
}

// Q = f1@qw+qb+pe (row-major), Kt = (f2@kw+kb+pe)^T -> [b][h][d][N], V row-major
__global__ void qkv_kernel(const float* __restrict__ feat1, const float* __restrict__ feat2,
                           const float* __restrict__ qw, const float* __restrict__ qb,
                           const float* __restrict__ kw, const float* __restrict__ kb,
                           const float* __restrict__ vw, const float* __restrict__ vb,
                           const float* __restrict__ pe,
                           float* __restrict__ Q, float* __restrict__ Kt, float* __restrict__ V,
                           int C, int N) {
  int t = threadIdx.x;            // 0..191
  int bn = blockIdx.x;            // b*N + n
  int b = bn / N, n = bn - b * N;
  const float* f1 = feat1 + (size_t)b * C * N + n;
  const float* f2 = feat2 + (size_t)b * C * N + n;
  float q = 0.f, k = 0.f, v = 0.f;
  for (int c = 0; c < C; ++c) {
    float a1 = f1[(size_t)c * N];
    float a2 = f2[(size_t)c * N];
    q = fmaf(a1, qw[c * TD + t], q);
    k = fmaf(a2, kw[c * TD + t], k);
    v = fmaf(a2, vw[c * TD + t], v);
  }
  float p = pe[n * TD + t];
  size_t o = (size_t)bn * TD + t;
  Q[o] = q + qb[t] + p;
  V[o] = v + vb[t];
  int h = t / HD, d = t - h * HD;
  Kt[(((size_t)b * 4 + h) * HD + d) * N + n] = k + kb[t] + p;
}

// ---------------- Stage A (nbh (b,h) pairs per launch) ----------------
// Block = (bh, 4 queries, key-range of RK). Cooperative score GEMM -> LDS,
// wave w owns query w with RK/64 keys/lane in registers, radix-select
// per-range top-128 with exact lowest-index ties, write (key u32, idx u16).
// Split correctness: a global-top-128 element has <=127 global predecessors
// under (key desc, idx asc) => <=127 in-range predecessors => in range top-128.
template <int N, int RK>
__global__ __launch_bounds__(256) void attnA_kernel(
    const float* __restrict__ Q, const float* __restrict__ Kt,
    unsigned* __restrict__ ckey, unsigned short* __restrict__ cidx, int bh0) {
  constexpr int R = N / RK;
  constexpr int NV4 = RK / 256;           // uint4 regs per lane (<=4)
  constexpr int nq = N / QB;
  __shared__ unsigned sb[QB * RK];        // 16 KB at RK=1024
  __shared__ float qv[QB][HD];
  __shared__ unsigned hist[4][256];

  const int tid = threadIdx.x;
  const int r = blockIdx.x % R;
  const int qg = (blockIdx.x / R) % nq;
  const int bhloc = blockIdx.x / (R * nq);
  const int bh = bh0 + bhloc;
  const int b = bh >> 2, h = bh & 3;
  const int q0 = qg * QB;
  const float scale = 0.14433756729740643f;  // 1/sqrt(48)

  if (tid < QB * HD) {
    int q = tid / HD, d = tid - q * HD;
    qv[q][d] = Q[((size_t)(b * N + q0 + q)) * TD + h * HD + d];
  }
  __syncthreads();

  const int w = tid >> 6, lane = tid & 63;
  const unsigned long long lanelt = (1ull << lane) - 1ull;
  const float* kt = Kt + ((size_t)(b * 4 + h) * HD) * N + r * RK;

  // ---- score GEMM for this range (4 keys x 4 queries per thread iter) ----
  for (int j0 = tid * 4; j0 < RK; j0 += 1024) {
    float4 acc[QB];
#pragma unroll
    for (int q = 0; q < QB; ++q) acc[q] = make_float4(0.f, 0.f, 0.f, 0.f);
#pragma unroll
    for (int d4 = 0; d4 < HD; d4 += 4) {
      float4 k0 = *reinterpret_cast<const float4*>(kt + (size_t)(d4 + 0) * N + j0);
      float4 k1 = *reinterpret_cast<const float4*>(kt + (size_t)(d4 + 1) * N + j0);
      float4 k2 = *reinterpret_cast<const float4*>(kt + (size_t)(d4 + 2) * N + j0);
      float4 k3 = *reinterpret_cast<const float4*>(kt + (size_t)(d4 + 3) * N + j0);
#pragma unroll
      for (int q = 0; q < QB; ++q) {
        float4 qq = *reinterpret_cast<const float4*>(&qv[q][d4]);
        acc[q].x = fmaf(qq.x, k0.x, acc[q].x); acc[q].x = fmaf(qq.y, k1.x, acc[q].x);
        acc[q].x = fmaf(qq.z, k2.x, acc[q].x); acc[q].x = fmaf(qq.w, k3.x, acc[q].x);
        acc[q].y = fmaf(qq.x, k0.y, acc[q].y); acc[q].y = fmaf(qq.y, k1.y, acc[q].y);
        acc[q].y = fmaf(qq.z, k2.y, acc[q].y); acc[q].y = fmaf(qq.w, k3.y, acc[q].y);
        acc[q].z = fmaf(qq.x, k0.z, acc[q].z); acc[q].z = fmaf(qq.y, k1.z, acc[q].z);
        acc[q].z = fmaf(qq.z, k2.z, acc[q].z); acc[q].z = fmaf(qq.w, k3.z, acc[q].z);
        acc[q].w = fmaf(qq.x, k0.w, acc[q].w); acc[q].w = fmaf(qq.y, k1.w, acc[q].w);
        acc[q].w = fmaf(qq.z, k2.w, acc[q].w); acc[q].w = fmaf(qq.w, k3.w, acc[q].w);
      }
    }
#pragma unroll
    for (int q = 0; q < QB; ++q) {
      uint4 kk;
      kk.x = f2o(acc[q].x * scale); kk.y = f2o(acc[q].y * scale);
      kk.z = f2o(acc[q].z * scale); kk.w = f2o(acc[q].w * scale);
      *reinterpret_cast<uint4*>(&sb[q * RK + j0]) = kk;
    }
  }
  __syncthreads();

  // ---- per-wave: keys -> registers (RK/64 per lane) ----
  uint4 kr[NV4];
#pragma unroll
  for (int i = 0; i < NV4; ++i)
    kr[i] = *reinterpret_cast<const uint4*>(&sb[w * RK + i * 256 + lane * 4]);

  // ---- radix select: 128th largest within range ----
  unsigned* hw = hist[w];
  unsigned kth = 0u, mask = 0u;
  int rem = KSEL;
#pragma unroll
  for (int shift = 24; shift >= 0; shift -= 8) {
#pragma unroll
    for (int i = 0; i < 4; ++i) hw[lane + i * 64] = 0u;
#pragma unroll
    for (int i = 0; i < NV4; ++i) {
      if ((kr[i].x & mask) == kth) atomicAdd(&hw[(kr[i].x >> shift) & 255u], 1u);
      if ((kr[i].y & mask) == kth) atomicAdd(&hw[(kr[i].y >> shift) & 255u], 1u);
      if ((kr[i].z & mask) == kth) atomicAdd(&hw[(kr[i].z >> shift) & 255u], 1u);
      if ((kr[i].w & mask) == kth) atomicAdd(&hw[(kr[i].w >> shift) & 255u], 1u);
    }
    int v[4], loc = 0;
#pragma unroll
    for (int i = 0; i < 4; ++i) { v[i] = (int)hw[255 - (lane * 4 + i)]; loc += v[i]; }
    int incl = loc;
#pragma unroll
    for (int off = 1; off < 64; off <<= 1) {
      int t = __shfl_up(incl, off, 64);
      if (lane >= off) incl += t;
    }
    int c = incl - loc;
    int selidx = -1, selexcl = 0;
#pragma unroll
    for (int i = 0; i < 4; ++i) {
      if (selidx < 0 && rem > c && rem <= c + v[i]) {
        selidx = 255 - (lane * 4 + i); selexcl = c;
      }
      c += v[i];
    }
    unsigned long long vote = __ballot(selidx >= 0);
    int src = __ffsll((long long)vote) - 1;
    selidx = __shfl(selidx, src, 64);
    selexcl = __shfl(selexcl, src, 64);
    rem -= selexcl;
    kth |= ((unsigned)selidx << shift);
    mask |= (0xFFu << shift);
  }
  const int need_eq = rem;

  // ---- compact: exact j-ascending tie ranking, write candidates ----
  unsigned* ok = ckey + (((size_t)bhloc * N + q0 + w) * R + r) * KSEL;
  unsigned short* oi = cidx + (((size_t)bhloc * N + q0 + w) * R + r) * KSEL;
  int selbase = 0, eqbase = 0;
#pragma unroll
  for (int i = 0; i < NV4; ++i) {
    const int jb = r * RK + i * 256 + lane * 4;   // global key index of .x
    const unsigned u0 = kr[i].x, u1 = kr[i].y, u2 = kr[i].z, u3 = kr[i].w;
    const bool e0 = (u0 == kth), e1 = (u1 == kth), e2 = (u2 == kth), e3 = (u3 == kth);
    const unsigned long long b0 = __ballot(e0), b1 = __ballot(e1), b2 = __ballot(e2), b3 = __ballot(e3);
    const int eqlt = __popcll(b0 & lanelt) + __popcll(b1 & lanelt) + __popcll(b2 & lanelt) + __popcll(b3 & lanelt);
    int eo = 0;
    const bool s0 = (u0 > kth) || (e0 && (eqbase + eqlt + eo) < need_eq); eo += e0 ? 1 : 0;
    const bool s1 = (u1 > kth) || (e1 && (eqbase + eqlt + eo) < need_eq); eo += e1 ? 1 : 0;
    const bool s2 = (u2 > kth) || (e2 && (eqbase + eqlt + eo) < need_eq); eo += e2 ? 1 : 0;
    const bool s3 = (u3 > kth) || (e3 && (eqbase + eqlt + eo) < need_eq); eo += e3 ? 1 : 0;
    const unsigned long long c0 = __ballot(s0), c1 = __ballot(s1), c2 = __ballot(s2), c3 = __ballot(s3);
    const int sellt = __popcll(c0 & lanelt) + __popcll(c1 & lanelt) + __popcll(c2 & lanelt) + __popcll(c3 & lanelt);
    int so = 0;
    if (s0) { int p = selbase + sellt + so; ok[p] = u0; oi[p] = (unsigned short)(jb + 0); } so += s0 ? 1 : 0;
    if (s1) { int p = selbase + sellt + so; ok[p] = u1; oi[p] = (unsigned short)(jb + 1); } so += s1 ? 1 : 0;
    if (s2) { int p = selbase + sellt + so; ok[p] = u2; oi[p] = (unsigned short)(jb + 2); } so += s2 ? 1 : 0;
    if (s3) { int p = selbase + sellt + so; ok[p] = u3; oi[p] = (unsigned short)(jb + 3); } so += s3 ? 1 : 0;
    eqbase += __popcll(b0) + __popcll(b1) + __popcll(b2) + __popcll(b3);
    selbase += __popcll(c0) + __popcll(c1) + __popcll(c2) + __popcll(c3);
  }
}

// ---------------- Stage B (nbh (b,h) pairs per launch) ----------------
// Wave per query: load CN candidates (ascending global index by construction,
// so ballot order == tie order), radix-select global top-128, softmax, gather V.
template <int CN>
__global__ __launch_bounds__(256) void attnB_kernel(
    const unsigned* __restrict__ ckey, const unsigned short* __restrict__ cidx,
    const float* __restrict__ V, float* __restrict__ O, int N, int bh0) {
  constexpr int CL = CN / 64;             // candidates per lane (8 or 2)
  __shared__ unsigned hist[4][256];
  __shared__ int idxb[4][KSEL];
  __shared__ float wb[4][KSEL];

  const int tid = threadIdx.x, w = tid >> 6, lane = tid & 63;
  const unsigned long long lanelt = (1ull << lane) - 1ull;
  const int g = blockIdx.x * 4 + w;       // query slot within this launch
  const int bhloc = g / N;
  const int qi = g - bhloc * N;
  const int bh = bh0 + bhloc;
  const int b = bh >> 2, h = bh & 3;

  unsigned ck[CL], ci[CL];
#pragma unroll
  for (int i = 0; i < CL; ++i) {
    ck[i] = ckey[(size_t)g * CN + i * 64 + lane];
    ci[i] = cidx[(size_t)g * CN + i * 64 + lane];
  }

  // global max (top-1 is always a candidate)
  unsigned mk = 0u;
#pragma unroll
  for (int i = 0; i < CL; ++i) mk = ck[i] > mk ? ck[i] : mk;
  for (int off = 32; off > 0; off >>= 1) {
    unsigned o = (unsigned)__shfl_xor((int)mk, off, 64);
    mk = o > mk ? o : mk;
  }
  const float mx = o2f(mk);

  // radix select 128th largest among CN candidates
  unsigned* hw = hist[w];
  unsigned kth = 0u, mask = 0u;
  int rem = KSEL;
#pragma unroll
  for (int shift = 24; shift >= 0; shift -= 8) {
#pragma unroll
    for (int i = 0; i < 4; ++i) hw[lane + i * 64] = 0u;
#pragma unroll
    for (int i = 0; i < CL; ++i)
      if ((ck[i] & mask) == kth) atomicAdd(&hw[(ck[i] >> shift) & 255u], 1u);
    int v[4], loc = 0;
#pragma unroll
    for (int i = 0; i < 4; ++i) { v[i] = (int)hw[255 - (lane * 4 + i)]; loc += v[i]; }
    int incl = loc;
#pragma unroll
    for (int off = 1; off < 64; off <<= 1) {
      int t = __shfl_up(incl, off, 64);
      if (lane >= off) incl += t;
    }
    int c = incl - loc;
    int selidx = -1, selexcl = 0;
#pragma unroll
    for (int i = 0; i < 4; ++i) {
      if (selidx < 0 && rem > c && rem <= c + v[i]) {
        selidx = 255 - (lane * 4 + i); selexcl = c;
      }
      c += v[i];
    }
    unsigned long long vote = __ballot(selidx >= 0);
    int src = __ffsll((long long)vote) - 1;
    selidx = __shfl(selidx, src, 64);
    selexcl = __shfl(selexcl, src, 64);
    rem -= selexcl;
    kth |= ((unsigned)selidx << shift);
    mask |= (0xFFu << shift);
  }
  const int need_eq = rem;

  // compact (candidate-array order == ascending global index == tie order)
  int selbase = 0, eqbase = 0;
  float lz = 0.f;
#pragma unroll
  for (int i = 0; i < CL; ++i) {
    const unsigned u = ck[i];
    const bool eq = (u == kth);
    const unsigned long long beq = __ballot(eq);
    const int eqrank = eqbase + __popcll(beq & lanelt);
    const bool sel = (u > kth) || (eq && eqrank < need_eq);
    const unsigned long long bsel = __ballot(sel);
    const int pos = selbase + __popcll(bsel & lanelt);
    if (sel) {
      float e = expf(o2f(u) - mx);
      idxb[w][pos] = (int)ci[i];
      wb[w][pos] = e;
      lz += e;
    }
    eqbase += __popcll(beq);
    selbase += __popcll(bsel);
  }
  for (int off = 32; off > 0; off >>= 1) lz += __shfl_xor(lz, off, 64);
  const float rz = 1.f / lz;

  // gather V (lane = dim)
  if (lane < HD) {
    float acc = 0.f;
#pragma unroll 4
    for (int p = 0; p < KSEL; ++p) {
      acc = fmaf(wb[w][p], V[((size_t)(b * N + idxb[w][p])) * TD + h * HD + lane], acc);
    }
    O[((size_t)(b * N + qi)) * TD + h * HD + lane] = acc * rz;
  }
}

// out[b, t, n0+nl] = O[b, n0+nl, :] . ow[:, t] + ob[t].
// 16-token LDS tile, 256 threads = 16 tokens x 16 channel-groups of 12.
// r10 lesson: old 64-token version had grid 128/32/8 blocks and 9216 serial
// loads/thread -> constant 164us latency floor at 6% occupancy.
#define OTOK 16
__global__ __launch_bounds__(256) void oproj_kernel(
    const float* __restrict__ O, const float* __restrict__ ow,
    const float* __restrict__ ob, float* __restrict__ out, int N) {
  __shared__ float otile[OTOK][TD + 1];   // 12.4 KB
  const int tid = threadIdx.x;
  const int nt = N / OTOK;
  const int b = blockIdx.x / nt;
  const int n0 = (blockIdx.x % nt) * OTOK;
  const float* obase = O + ((size_t)(b * N + n0)) * TD;
  for (int idx = tid * 4; idx < OTOK * TD; idx += 1024) {
    float4 v = *reinterpret_cast<const float4*>(obase + idx);
    int r = idx / TD, c = idx - r * TD;
    otile[r][c] = v.x; otile[r][c + 1] = v.y; otile[r][c + 2] = v.z; otile[r][c + 3] = v.w;
  }
  __syncthreads();
  const int nl = tid & 15;            // token
  const int ts = (tid >> 4) * 12;     // channel group (16 x 12 = 192)
  float a0 = 0.f, a1 = 0.f, a2 = 0.f, a3 = 0.f, a4 = 0.f, a5 = 0.f,
        a6 = 0.f, a7 = 0.f, a8 = 0.f, a9 = 0.f, a10 = 0.f, a11 = 0.f;
  for (int c = 0; c < TD; ++c) {
    float oval = otile[nl][c];
    const float* wr = ow + c * TD + ts;
    float4 w0 = *reinterpret_cast<const float4*>(wr);
    float4 w1 = *reinterpret_cast<const float4*>(wr + 4);
    float4 w2 = *reinterpret_cast<const float4*>(wr + 8);
    a0 = fmaf(oval, w0.x, a0); a1 = fmaf(oval, w0.y, a1);
    a2 = fmaf(oval, w0.z, a2); a3 = fmaf(oval, w0.w, a3);
    a4 = fmaf(oval, w1.x, a4); a5 = fmaf(oval, w1.y, a5);
    a6 = fmaf(oval, w1.z, a6); a7 = fmaf(oval, w1.w, a7);
    a8 = fmaf(oval, w2.x, a8); a9 = fmaf(oval, w2.y, a9);
    a10 = fmaf(oval, w2.z, a10); a11 = fmaf(oval, w2.w, a11);
  }
  const size_t obase2 = ((size_t)b * TD + ts) * N + n0 + nl;
  out[obase2 + 0 * N] = a0 + ob[ts + 0];
  out[obase2 + 1 * N] = a1 + ob[ts + 1];
  out[obase2 + 2 * N] = a2 + ob[ts + 2];
  out[obase2 + 3 * N] = a3 + ob[ts + 3];
  out[obase2 + 4 * N] = a4 + ob[ts + 4];
  out[obase2 + 5 * N] = a5 + ob[ts + 5];
  out[obase2 + 6 * N] = a6 + ob[ts + 6];
  out[obase2 + 7 * N] = a7 + ob[ts + 7];
  out[obase2 + 8 * N] = a8 + ob[ts + 8];
  out[obase2 + 9 * N] = a9 + ob[ts + 9];
  out[obase2 + 10 * N] = a10 + ob[ts + 10];
  out[obase2 + 11 * N] = a11 + ob[ts + 11];
}

extern "C" void kernel_launch(void* const* d_in, const int* in_sizes, int n_in,
                              void* d_out, int out_size, void* d_ws, size_t ws_size,
                              hipStream_t stream) {
  const int B = 2;
  const int Cs[3] = {64, 128, 192};
  const int Hs[3] = {64, 32, 16};
  const size_t out_off[3] = {0,
                             (size_t)2 * TD * 64 * 64,
                             (size_t)2 * TD * 64 * 64 + (size_t)2 * TD * 32 * 32};

  float* ws = (float*)d_ws;
  float* pe = ws;                                 // 3.1 MB
  float* Q = pe + (size_t)4096 * TD;              // each 6.3 MB
  float* Kt = Q + (size_t)B * 4096 * TD;
  float* V = Kt + (size_t)B * 4096 * TD;
  float* Obuf = V + (size_t)B * 4096 * TD;
  // candidate buffers: 4096x512 slots (lvl0 single (b,h)) = 8.4 + 4.2 MB;
  // lvl1 batched (8x1024x128 = 1M slots) and lvl2 (8x256x128 = 0.26M) also fit.
  unsigned* ckey = (unsigned*)(Obuf + (size_t)B * 4096 * TD);
  unsigned short* cidx = (unsigned short*)(ckey + (size_t)4096 * 512);
  // total ws usage ~41 MB (proven safe in r10)

  for (int lvl = 0; lvl < 3; ++lvl) {
    int C = Cs[lvl], H = Hs[lvl], W = H, N = H * W;
    const float* feat1 = (const float*)d_in[lvl * 2 + 0];
    const float* feat2 = (const float*)d_in[lvl * 2 + 1];
    const float* qw = (const float*)d_in[6 + lvl * 8 + 0];
    const float* qb = (const float*)d_in[6 + lvl * 8 + 1];
    const float* kw = (const float*)d_in[6 + lvl * 8 + 2];
    const float* kb = (const float*)d_in[6 + lvl * 8 + 3];
    const float* vw = (const float*)d_in[6 + lvl * 8 + 4];
    const float* vb = (const float*)d_in[6 + lvl * 8 + 5];
    const float* ow = (const float*)d_in[6 + lvl * 8 + 6];
    const float* ob = (const float*)d_in[6 + lvl * 8 + 7];

    pe_kernel<<<N, TD, 0, stream>>>(pe, W);
    qkv_kernel<<<B * N, TD, 0, stream>>>(feat1, feat2, qw, qb, kw, kb, vw, vb, pe, Q, Kt, V, C, N);

    if (N == 4096) {
      // lvl0: candidate buffer fits one (b,h) -> 8 sequential pairs
      for (int bh = 0; bh < 8; ++bh) {
        attnA_kernel<4096, 1024><<<(4096 / QB) * 4, 256, 0, stream>>>(Q, Kt, ckey, cidx, bh);
        attnB_kernel<512><<<4096 / 4, 256, 0, stream>>>(ckey, cidx, V, Obuf, 4096, bh);
      }
    } else if (N == 1024) {
      // all 8 (b,h) in one launch: 2048 blocks each
      attnA_kernel<1024, 1024><<<8 * (1024 / QB), 256, 0, stream>>>(Q, Kt, ckey, cidx, 0);
      attnB_kernel<128><<<8 * 1024 / 4, 256, 0, stream>>>(ckey, cidx, V, Obuf, 1024, 0);
    } else {
      attnA_kernel<256, 256><<<8 * (256 / QB), 256, 0, stream>>>(Q, Kt, ckey, cidx, 0);
      attnB_kernel<128><<<8 * 256 / 4, 256, 0, stream>>>(ckey, cidx, V, Obuf, 256, 0);
    }
    oproj_kernel<<<B * (N / OTOK), 256, 0, stream>>>(Obuf, ow, ob, (float*)d_out + out_off[lvl], N);
  }
}